// Round 14
// baseline (542.183 us; speedup 1.0000x reference)
//
#include <hip/hip_runtime.h>
#include <math.h>

#define NN 8000   // nodes
#define CD 64     // node feature dim / C_OUT
#define DG 16     // neighbors per node
#define HD 128    // GRU hidden
#define G3 384    // 3*HD
#define TT 4      // walk steps
// Worst-case f32 noisy-score error bound ~1e-3; MARGIN = 4e-3 (proven r8-r13).
#define MARGIN 4e-3f
#define FIXB 600  // fix-role blocks in tail_kernel (4 fail entries each)

#if __has_builtin(__builtin_amdgcn_rcpf)
#define RCP(x) __builtin_amdgcn_rcpf(x)
#else
#define RCP(x) (1.f/(x))
#endif

// fast f32 (walk + wgru; error ~1e-6 << MARGIN)
__device__ __forceinline__ float fsig (float x){ return RCP(1.f + __expf(-x)); }
__device__ __forceinline__ float ftanh(float x){ return 1.f - 2.f*RCP(1.f + __expf(2.f*x)); }

// fast f64 exp: range-reduced 13-term Horner, ~3 ulp (validated r9-r13).
__device__ __forceinline__ double fexp64(double x){
    const double LOG2E  = 1.4426950408889634074;
    const double LN2_HI = 6.93147180369123816490e-01;
    const double LN2_LO = 1.90821492927058770002e-10;
    x = fmin(fmax(x, -700.0), 700.0);
    double fn = rint(x * LOG2E);
    double r  = fma(-fn, LN2_HI, x);
    r = fma(-fn, LN2_LO, r);
    double p = 1.6059043836821613e-10;            // 1/13!
    p = fma(p, r, 2.0876756987868099e-09);
    p = fma(p, r, 2.5052108385441719e-08);
    p = fma(p, r, 2.7557319223985893e-07);
    p = fma(p, r, 2.7557319223985888e-06);
    p = fma(p, r, 2.4801587301587302e-05);
    p = fma(p, r, 1.9841269841269841e-04);
    p = fma(p, r, 1.3888888888888889e-03);
    p = fma(p, r, 8.3333333333333332e-03);
    p = fma(p, r, 4.1666666666666664e-02);
    p = fma(p, r, 1.6666666666666666e-01);
    p = fma(p, r, 0.5);
    p = fma(p, r, 1.0);
    p = fma(p, r, 1.0);
    long long bits = __double_as_longlong(p) + ((long long)(int)fn << 52);
    return __longlong_as_double(bits);
}
__device__ __forceinline__ double sig64f (double x){ return 1.0/(1.0 + fexp64(-x)); }
__device__ __forceinline__ double tanh64f(double x){ return 1.0 - 2.0/(fexp64(2.0*x) + 1.0); }

// XG precompute in f64; emit packed-hi [n][64][8] (+ optional residual [n][64][6]).
__global__ __launch_bounds__(384) void xg_kernel(const float* __restrict__ A,
    const float* __restrict__ W, const float* __restrict__ b,
    float* __restrict__ hiP, float* __restrict__ loP)
{
    __shared__ float a_s[8][64];
    const int g  = threadIdx.x;        // 0..383
    const int l  = g & 63, q = g >> 6;
    const int n0 = blockIdx.x * 8;
    for (int idx = threadIdx.x; idx < 8*64; idx += 384)
        a_s[idx>>6][idx&63] = A[(size_t)n0*64 + idx];
    __syncthreads();
    double acc[8];
    const double bg = (double)b[g];
#pragma unroll
    for (int j=0;j<8;j++) acc[j] = bg;
    for (int c=0;c<64;c++){
        const double w = (double)W[c*G3 + g];
#pragma unroll
        for (int j=0;j<8;j++) acc[j] += (double)a_s[j][c]*w;
    }
#pragma unroll
    for (int j=0;j<8;j++){
        const size_t base = (size_t)(n0+j)*64 + l;
        const float hi = (float)acc[j];
        hiP[base*8 + q] = hi;
        if (q < 2) hiP[base*8 + 6 + q] = 0.f;       // zero pad slots
        if (loP) loP[base*6 + q] = (float)(acc[j] - (double)hi);
    }
}

// Repack Wh [k][384] -> [k][lane][8] (slot m = W[k][64*m+lane], slots 6,7 = 0).
__global__ __launch_bounds__(256) void repack_kernel(const float* __restrict__ W,
                                                     float* __restrict__ P)
{
    const int idx = blockIdx.x*256 + threadIdx.x;   // 0 .. 128*512-1
    const int k = idx >> 9, rem = idx & 511, l = rem >> 3, s = rem & 7;
    P[idx] = (s < 6) ? W[k*G3 + s*64 + l] : 0.f;
}

// Phase 1: pure-f32 walk (r13 structure, passing). Adds trip_flag per node.
__global__ __launch_bounds__(256) void walk_kernel(
    const int*   __restrict__ nbrs,  const float* __restrict__ noise,
    const float* __restrict__ XGfP,  const float* __restrict__ dWhP,
    const float* __restrict__ dbh,   const float* __restrict__ dWo,
    const float* __restrict__ dbo,
    int* __restrict__ paths, int* __restrict__ fail_cnt, int* __restrict__ fail_list,
    int* __restrict__ trip_flag, float* __restrict__ out)
{
    __shared__ float hf_s[4][HD];
    __shared__ float part_s[4][4][6][64];

    const int wid  = threadIdx.x >> 6;
    const int lane = threadIdx.x & 63;
    const int node = blockIdx.x*4 + wid;

    float h0 = 0.f, h1 = 0.f;
    float dbhf[6], hgf[6];
#pragma unroll
    for (int m=0;m<6;m++){ dbhf[m] = dbh[lane+64*m]; hgf[m] = dbhf[m]; }
    const float wo0f0 = dWo[lane*CD];
    const float wo0f1 = dWo[(lane+64)*CD];
    const float dbo0f = dbo[0];

    int  cur = node;
    int  ch0=0, ch1=0, ch2=0, ch3=0;
    bool pushed = false;

    for (int t=0;t<TT;t++){
        if      (t==0) ch0 = cur;
        else if (t==1) ch1 = cur;
        else if (t==2) ch2 = cur;
        else           ch3 = cur;

        // ---- extend prefix (packed row: 2 x b128) ----
        {
            const float4* xr = (const float4*)(XGfP + ((size_t)cur*64 + lane)*8);
            const float4 A = xr[0], B = xr[1];
            float r = fsig (A.x + hgf[0]);
            float z = fsig (A.z + hgf[2]);
            float n = ftanh(B.x + r*hgf[4]);
            h0 = (1.f-z)*n + z*h0;
            r = fsig (A.y + hgf[1]);
            z = fsig (A.w + hgf[3]);
            n = ftanh(B.y + r*hgf[5]);
            h1 = (1.f-z)*n + z*h1;
        }
        hf_s[wid][lane] = h0;  hf_s[wid][lane+64] = h1;
        __syncthreads();

        // ---- cooperative matvec ----
        {
            float pacc[4][6];
#pragma unroll
            for (int j=0;j<4;j++)
#pragma unroll
                for (int m=0;m<6;m++) pacc[j][m] = 0.f;
            const float4* wr = (const float4*)(dWhP + (size_t)lane*8);
#pragma unroll 4
            for (int kk=0; kk<32; kk++){
                const int k = wid*32 + kk;
                const float4 W0 = wr[k*128], W1 = wr[k*128+1];
#pragma unroll
                for (int j=0;j<4;j++){
                    const float hk = hf_s[j][k];
                    pacc[j][0] += hk*W0.x; pacc[j][1] += hk*W0.y;
                    pacc[j][2] += hk*W0.z; pacc[j][3] += hk*W0.w;
                    pacc[j][4] += hk*W1.x; pacc[j][5] += hk*W1.y;
                }
            }
#pragma unroll
            for (int j=0;j<4;j++)
#pragma unroll
                for (int m=0;m<6;m++) part_s[wid][j][m][lane] = pacc[j][m];
        }
        __syncthreads();

#pragma unroll
        for (int m=0;m<6;m++)
            hgf[m] = dbhf[m] + part_s[0][wid][m][lane] + part_s[1][wid][m][lane]
                             + part_s[2][wid][m][lane] + part_s[3][wid][m][lane];

        // ---- 16 candidates, per-wave ----
        int   nbrv = (lane < DG) ? nbrs[(size_t)cur*DG + lane] : 0;
        float nz   = (lane < DG) ? noise[((size_t)t*NN + node)*DG + lane] : 0.f;
        float lf = -3.0e38f;
#pragma unroll
        for (int g=0; g<4; g++){
            float4 CA[4], CB[4];
#pragma unroll
            for (int j=0;j<4;j++){
                const int nd = __shfl(nbrv, g*4+j);
                const float4* cr = (const float4*)(XGfP + ((size_t)nd*64 + lane)*8);
                CA[j] = cr[0];  CB[j] = cr[1];
            }
            float part[4];
#pragma unroll
            for (int j=0;j<4;j++){
                float r = fsig (CA[j].x + hgf[0]);
                float z = fsig (CA[j].z + hgf[2]);
                float n = ftanh(CB[j].x + r*hgf[4]);
                part[j]  = ((1.f-z)*n + z*h0) * wo0f0;
                r = fsig (CA[j].y + hgf[1]);
                z = fsig (CA[j].w + hgf[3]);
                n = ftanh(CB[j].y + r*hgf[5]);
                part[j] += ((1.f-z)*n + z*h1) * wo0f1;
            }
#pragma unroll
            for (int off=32; off>0; off>>=1){
#pragma unroll
                for (int j=0;j<4;j++) part[j] += __shfl_xor(part[j], off);
            }
#pragma unroll
            for (int j=0;j<4;j++) if (lane == g*4+j) lf = part[j] + dbo0f;
        }

        // ---- softmax + noisy argmax + top-2 margin ----
        float v  = (lane < DG) ? lf : -3.0e38f;
        float mx = v;
#pragma unroll
        for (int off=32; off>0; off>>=1) mx = fmaxf(mx, __shfl_xor(mx, off));
        float e = (lane < DG) ? __expf(v - mx) : 0.f;
        float s = e;
#pragma unroll
        for (int off=32; off>0; off>>=1) s += __shfl_xor(s, off);
        const float normf = mx + __logf(s);

        float noisyf = (lane < DG) ? __expf(v - normf) + 0.01f*nz : -3.0e38f;
        int   idx = lane;
        float bv  = noisyf;
#pragma unroll
        for (int off=32; off>0; off>>=1){
            float ov = __shfl_xor(bv, off);
            int   oi = __shfl_xor(idx, off);
            if (ov > bv || (ov == bv && oi < idx)){ bv = ov; idx = oi; }
        }
        float sv = (lane == idx || lane >= DG) ? -3.0e38f : noisyf;
#pragma unroll
        for (int off=32; off>0; off>>=1) sv = fmaxf(sv, __shfl_xor(sv, off));

        const bool trip = (bv - sv) < MARGIN;   // wave-uniform
        if (trip && !pushed){
            if (lane == 0){
                const int slot = atomicAdd(fail_cnt, 1);
                if (slot < NN) fail_list[slot] = node | (t << 16);
            }
            pushed = true;
        }

        const float lpf = __shfl(v, idx) - normf;
        if (lane == 0) out[NN*CD + node*TT + t] = lpf;
        cur = __shfl(nbrv, idx);
    }

    if (lane == 0){
        int* p = paths + (size_t)node*8;
        p[0]=ch0; p[1]=ch1; p[2]=ch2; p[3]=ch3; p[4]=cur;
        trip_flag[node] = pushed ? 1 : 0;
    }
}

// Block-cooperative w-GRU over one 5-node walk per wave (4 nodes per block).
// hwm = float[4][HD] (in smem), pbuf = float[4][4][6][64] (in smem).
__device__ __forceinline__ void run_wgru4(
    float* hwm, float* pbuf, const int* w5, const bool doWrite, const int node,
    const float* __restrict__ XGwP, const float* __restrict__ wWhP,
    const float* __restrict__ wbh,  const float* __restrict__ wWo,
    const float* __restrict__ wbo,  float* __restrict__ out,
    const int wid, const int lane)
{
    float h0 = 0.f, h1 = 0.f;
    float wb[6], hg[6];
#pragma unroll
    for (int m=0;m<6;m++){ wb[m] = wbh[lane+64*m]; hg[m] = wb[m]; }

#pragma unroll
    for (int s=0; s<=TT; s++){
        const int c = w5[s];
        const float4* xr = (const float4*)(XGwP + ((size_t)c*64 + lane)*8);
        const float4 A = xr[0], B = xr[1];
        float r = fsig (A.x + hg[0]);
        float z = fsig (A.z + hg[2]);
        float n = ftanh(B.x + r*hg[4]);
        h0 = (1.f-z)*n + z*h0;
        r = fsig (A.y + hg[1]);
        z = fsig (A.w + hg[3]);
        n = ftanh(B.y + r*hg[5]);
        h1 = (1.f-z)*n + z*h1;
        if (s < TT){
            hwm[wid*HD + lane] = h0;  hwm[wid*HD + lane + 64] = h1;
            __syncthreads();
            float pacc[4][6];
#pragma unroll
            for (int j=0;j<4;j++)
#pragma unroll
                for (int m=0;m<6;m++) pacc[j][m] = 0.f;
            const float4* wv = (const float4*)(wWhP + (size_t)lane*8);
#pragma unroll 4
            for (int kk=0; kk<32; kk++){
                const int k = wid*32 + kk;
                const float4 W0 = wv[k*128], W1 = wv[k*128+1];
#pragma unroll
                for (int j=0;j<4;j++){
                    const float hk = hwm[j*HD + k];
                    pacc[j][0] += hk*W0.x; pacc[j][1] += hk*W0.y;
                    pacc[j][2] += hk*W0.z; pacc[j][3] += hk*W0.w;
                    pacc[j][4] += hk*W1.x; pacc[j][5] += hk*W1.y;
                }
            }
#pragma unroll
            for (int j=0;j<4;j++)
#pragma unroll
                for (int m=0;m<6;m++) pbuf[((wid*4+j)*6+m)*64 + lane] = pacc[j][m];
            __syncthreads();
#pragma unroll
            for (int m=0;m<6;m++)
                hg[m] = wb[m] + pbuf[((0*4+wid)*6+m)*64 + lane]
                              + pbuf[((1*4+wid)*6+m)*64 + lane]
                              + pbuf[((2*4+wid)*6+m)*64 + lane]
                              + pbuf[((3*4+wid)*6+m)*64 + lane];
        }
    }
    hwm[wid*HD + lane] = h0;  hwm[wid*HD + lane + 64] = h1;
    float acc = wbo[lane];                 // CD == 64 == wave width
    const float* wcol = wWo + lane;
    for (int i=0;i<HD;i++) acc += hwm[wid*HD + i] * wcol[(size_t)i*CD];
    if (doWrite) out[(size_t)node*CD + lane] = acc;
}

// Tail: blocks < FIXB do the exact-f64 fix (grid-stride over fail list; 3-stage
// 28KB LDS reduction) then the w-GRU for their nodes; remaining blocks do the
// w-GRU for all nodes, writing only untripped ones (fix-role writes tripped).
// Concurrent wgru throughput work hides fix latency.
__global__ __launch_bounds__(256) void tail_kernel(
    const int*   __restrict__ nbrs,  const float* __restrict__ noise,
    const float* __restrict__ XGfP,  const float* __restrict__ XGrP,
    const float* __restrict__ dWhP,  const float* __restrict__ dbh,
    const float* __restrict__ dWo,   const float* __restrict__ dbo,
    const float* __restrict__ XGwP,  const float* __restrict__ wWhP,
    const float* __restrict__ wbh,   const float* __restrict__ wWo,
    const float* __restrict__ wbo,
    const int* __restrict__ fail_cnt, const int* __restrict__ fail_list,
    const int* __restrict__ trip_flag,
    int* __restrict__ paths, float* __restrict__ out)
{
    __shared__ double smem[3584];            // 28672 B union
    const int wid  = threadIdx.x >> 6;
    const int lane = threadIdx.x & 63;

    if (blockIdx.x >= FIXB){
        // -------- WGRU role: 4 nodes per block --------
        const int node = (blockIdx.x - FIXB)*4 + wid;
        float* hwm  = (float*)smem;          // [4][HD]
        float* pbuf = (float*)(smem + 256);  // [4][4][6][64]
        int w5[5];
        const int* p = paths + (size_t)node*8;
#pragma unroll
        for (int s=0;s<5;s++) w5[s] = p[s];  // tripped nodes: value discarded
        const bool doW = (trip_flag[node] == 0);
        run_wgru4(hwm, pbuf, w5, doW, node, XGwP, wWhP, wbh, wWo, wbo,
                  out, wid, lane);
        return;
    }

    // -------- FIX role --------
    double* h_s  = smem;                     // [4][HD]
    double* dbuf = smem + 512;               // [2][4][6][64]
    const int count = min(fail_cnt[0], NN);

    double db64[6];
#pragma unroll
    for (int m=0;m<6;m++) db64[m] = (double)dbh[lane+64*m];
    const double wo0d0 = (double)dWo[lane*CD];
    const double wo0d1 = (double)dWo[(lane+64)*CD];
    const double dbo0d = (double)dbo[0];

    for (int base = blockIdx.x*4; base < count; base += FIXB*4){
        const int  ii     = base + wid;
        const bool active = (ii < count);
        const int  entry  = active ? fail_list[ii] : 0;   // idle waves ride node 0
        const int  node   = entry & 0xFFFF;
        const int  t0     = active ? (entry >> 16) : TT;
        const int* pw     = paths + (size_t)node*8;

        double H0 = 0.0, H1 = 0.0;
        double g64[6];
#pragma unroll
        for (int m=0;m<6;m++) g64[m] = db64[m];
        int cur = node;
        int c0=0,c1=0,c2=0,c3=0;

        for (int t=0;t<TT;t++){
            if      (t==0) c0 = cur;
            else if (t==1) c1 = cur;
            else if (t==2) c2 = cur;
            else           c3 = cur;

            // ---- extend (f64 = hi + residual) ----
            {
                const size_t b = (size_t)cur*64 + lane;
                const float* hi = XGfP + b*8;
                const float* lo = XGrP + b*6;
                double r = sig64f (((double)hi[0]+(double)lo[0]) + g64[0]);
                double z = sig64f (((double)hi[2]+(double)lo[2]) + g64[2]);
                double n = tanh64f(((double)hi[4]+(double)lo[4]) + r*g64[4]);
                H0 = (1.0-z)*n + z*H0;
                r = sig64f (((double)hi[1]+(double)lo[1]) + g64[1]);
                z = sig64f (((double)hi[3]+(double)lo[3]) + g64[3]);
                n = tanh64f(((double)hi[5]+(double)lo[5]) + r*g64[5]);
                H1 = (1.0-z)*n + z*H1;
            }
            h_s[wid*HD + lane] = H0;  h_s[wid*HD + lane + 64] = H1;
            __syncthreads();                            // (1) h ready

            // ---- cooperative f64 matvec, 3-stage pairwise reduction ----
            double pacc[4][6];
#pragma unroll
            for (int j=0;j<4;j++)
#pragma unroll
                for (int m=0;m<6;m++) pacc[j][m] = 0.0;
            {
                const float4* wv = (const float4*)(dWhP + (size_t)lane*8);
#pragma unroll 4
                for (int kk=0; kk<32; kk++){
                    const int k = wid*32 + kk;
                    const float4 W0 = wv[k*128], W1 = wv[k*128+1];
#pragma unroll
                    for (int j=0;j<4;j++){
                        const double hk = h_s[j*HD + k];
                        pacc[j][0] += hk*(double)W0.x; pacc[j][1] += hk*(double)W0.y;
                        pacc[j][2] += hk*(double)W0.z; pacc[j][3] += hk*(double)W0.w;
                        pacc[j][4] += hk*(double)W1.x; pacc[j][5] += hk*(double)W1.y;
                    }
                }
            }
            if (wid >= 2){
#pragma unroll
                for (int j=0;j<4;j++)
#pragma unroll
                    for (int m=0;m<6;m++)
                        dbuf[(((wid-2)*4+j)*6+m)*64 + lane] = pacc[j][m];
            }
            __syncthreads();                            // (2) writers 2,3 published
            if (wid < 2){
#pragma unroll
                for (int j=0;j<4;j++)
#pragma unroll
                    for (int m=0;m<6;m++){
                        pacc[j][m] += dbuf[((wid*4+j)*6+m)*64 + lane];
                        dbuf[((wid*4+j)*6+m)*64 + lane] = pacc[j][m];
                    }
            }
            __syncthreads();                            // (3) pair sums published
#pragma unroll
            for (int m=0;m<6;m++)
                g64[m] = db64[m] + dbuf[((0*4+wid)*6+m)*64 + lane]
                                 + dbuf[((1*4+wid)*6+m)*64 + lane];

            // ---- certified prefix: skip scoring, follow recorded path ----
            if (t < t0){
                cur = pw[t+1];
                continue;                               // no barriers below
            }

            // ---- 16 candidates f64, 4 groups of 4 with prefetch ----
            int   nbrv = (lane < DG) ? nbrs[(size_t)cur*DG + lane] : 0;
            float nz   = (lane < DG) ? noise[((size_t)t*NN + node)*DG + lane] : 0.f;
            double lv = -1e300;
#pragma unroll
            for (int g=0; g<4; g++){
                float ch[4][6], cl[4][6];
#pragma unroll
                for (int j=0;j<4;j++){
                    const int nd = __shfl(nbrv, g*4+j);
                    const size_t b = (size_t)nd*64 + lane;
                    const float* hi = XGfP + b*8;
                    const float* lo = XGrP + b*6;
#pragma unroll
                    for (int q=0;q<6;q++){ ch[j][q]=hi[q]; cl[j][q]=lo[q]; }
                }
#pragma unroll
                for (int j=0;j<4;j++){
                    double r = sig64f (((double)ch[j][0]+(double)cl[j][0]) + g64[0]);
                    double z = sig64f (((double)ch[j][2]+(double)cl[j][2]) + g64[2]);
                    double n = tanh64f(((double)ch[j][4]+(double)cl[j][4]) + r*g64[4]);
                    double part = ((1.0-z)*n + z*H0) * wo0d0;
                    r = sig64f (((double)ch[j][1]+(double)cl[j][1]) + g64[1]);
                    z = sig64f (((double)ch[j][3]+(double)cl[j][3]) + g64[3]);
                    n = tanh64f(((double)ch[j][5]+(double)cl[j][5]) + r*g64[5]);
                    part += ((1.0-z)*n + z*H1) * wo0d1;
#pragma unroll
                    for (int off=32; off>0; off>>=1) part += __shfl_xor(part, off);
                    if (lane == g*4+j) lv = part + dbo0d;
                }
            }

            // ---- softmax + noisy argmax (identical numerics to r9-r13) ----
            double dv = (lane < DG) ? lv : -1e300;
            double dmx = dv;
#pragma unroll
            for (int off=32; off>0; off>>=1) dmx = fmax(dmx, __shfl_xor(dmx, off));
            double de = (lane < DG) ? fexp64(dv - dmx) : 0.0;
            double ds = de;
#pragma unroll
            for (int off=32; off>0; off>>=1) ds += __shfl_xor(ds, off);
            const double dnorm = dmx + log(ds);
            double dnoisy = (lane < DG) ? fexp64(dv - dnorm) + 0.01*(double)nz : -1e300;
            int di = lane;
#pragma unroll
            for (int off=32; off>0; off>>=1){
                double ov = __shfl_xor(dnoisy, off);
                int    oi = __shfl_xor(di, off);
                if (ov > dnoisy || (ov == dnoisy && oi < di)){ dnoisy = ov; di = oi; }
            }
            const double lpfix = __shfl(dv, di) - dnorm;
            if (active && lane == 0) out[NN*CD + node*TT + t] = (float)lpfix;
            cur = __shfl(nbrv, di);
        }

        const int w5[5] = {c0, c1, c2, c3, cur};
        if (active && lane == 0){
            int* p = paths + (size_t)node*8;
            p[0]=c0; p[1]=c1; p[2]=c2; p[3]=c3; p[4]=cur;
        }
        __syncthreads();                 // smem handoff d-fix -> w-GRU
        run_wgru4((float*)smem, (float*)(smem + 256), w5, active, node,
                  XGwP, wWhP, wbh, wWo, wbo, out, wid, lane);
        __syncthreads();                 // before next grid-stride iteration
    }
}

extern "C" void kernel_launch(void* const* d_in, const int* in_sizes, int n_in,
                              void* d_out, int out_size, void* d_ws, size_t ws_size,
                              hipStream_t stream)
{
    const float* attr  = (const float*)d_in[0];
    const int*   nbrs  = (const int*)  d_in[1];
    const float* noise = (const float*)d_in[2];
    const float* dWx = (const float*)d_in[3];
    const float* dWh = (const float*)d_in[4];
    const float* dbx = (const float*)d_in[5];
    const float* dbh = (const float*)d_in[6];
    const float* dWo = (const float*)d_in[7];
    const float* dbo = (const float*)d_in[8];
    const float* wWx = (const float*)d_in[9];
    const float* wWh = (const float*)d_in[10];
    const float* wbx = (const float*)d_in[11];
    const float* wbh = (const float*)d_in[12];
    const float* wWo = (const float*)d_in[13];
    const float* wbo = (const float*)d_in[14];
    float* out = (float*)d_out;

    char* ws = (char*)d_ws;
    float* XGfP      = (float*)(ws);                 // 16,384,000 B
    float* XGrP      = (float*)(ws + 16384000);      // 12,288,000 B
    float* XGwP      = (float*)(ws + 28672000);      // 16,384,000 B
    float* dWhP      = (float*)(ws + 45056000);      // 262,144 B
    float* wWhP      = (float*)(ws + 45318144);      // 262,144 B
    int*   paths     = (int*)  (ws + 45580288);      // 256,000 B
    int*   fail_list = (int*)  (ws + 45836288);      // 32,000 B
    int*   trip_flag = (int*)  (ws + 45868288);      // 32,000 B
    int*   fail_cnt  = (int*)  (ws + 45900288);      // 4 B  (total ~45.9 MB)

    hipMemsetAsync(fail_cnt, 0, sizeof(int), stream);

    xg_kernel<<<NN/8, G3, 0, stream>>>(attr, dWx, dbx, XGfP, XGrP);
    xg_kernel<<<NN/8, G3, 0, stream>>>(attr, wWx, wbx, XGwP, nullptr);
    repack_kernel<<<(HD*64*8)/256, 256, 0, stream>>>(dWh, dWhP);
    repack_kernel<<<(HD*64*8)/256, 256, 0, stream>>>(wWh, wWhP);

    walk_kernel<<<NN/4, 256, 0, stream>>>(nbrs, noise, XGfP, dWhP,
                                          dbh, dWo, dbo,
                                          paths, fail_cnt, fail_list, trip_flag, out);
    tail_kernel<<<FIXB + NN/4, 256, 0, stream>>>(nbrs, noise, XGfP, XGrP,
                                                 dWhP, dbh, dWo, dbo,
                                                 XGwP, wWhP, wbh, wWo, wbo,
                                                 fail_cnt, fail_list, trip_flag,
                                                 paths, out);
}

// Round 15
// 525.268 us; speedup vs baseline: 1.0322x; 1.0322x over previous
//
#include <hip/hip_runtime.h>
#include <math.h>

#define NN 8000   // nodes
#define CD 64     // node feature dim / C_OUT
#define DG 16     // neighbors per node
#define HD 128    // GRU hidden
#define G3 384    // 3*HD
#define TT 4      // walk steps
// Worst-case f32 noisy-score error bound ~1e-3; MARGIN = 4e-3 (proven r8-r14).
#define MARGIN 4e-3f

#if __has_builtin(__builtin_amdgcn_rcpf)
#define RCP(x) __builtin_amdgcn_rcpf(x)
#else
#define RCP(x) (1.f/(x))
#endif

// fast f32 (walk + wgru; error ~1e-6 << MARGIN)
__device__ __forceinline__ float fsig (float x){ return RCP(1.f + __expf(-x)); }
__device__ __forceinline__ float ftanh(float x){ return 1.f - 2.f*RCP(1.f + __expf(2.f*x)); }

// fast f64 exp: range-reduced 13-term Horner, ~3 ulp (validated r9-r14).
__device__ __forceinline__ double fexp64(double x){
    const double LOG2E  = 1.4426950408889634074;
    const double LN2_HI = 6.93147180369123816490e-01;
    const double LN2_LO = 1.90821492927058770002e-10;
    x = fmin(fmax(x, -700.0), 700.0);
    double fn = rint(x * LOG2E);
    double r  = fma(-fn, LN2_HI, x);
    r = fma(-fn, LN2_LO, r);
    double p = 1.6059043836821613e-10;            // 1/13!
    p = fma(p, r, 2.0876756987868099e-09);
    p = fma(p, r, 2.5052108385441719e-08);
    p = fma(p, r, 2.7557319223985893e-07);
    p = fma(p, r, 2.7557319223985888e-06);
    p = fma(p, r, 2.4801587301587302e-05);
    p = fma(p, r, 1.9841269841269841e-04);
    p = fma(p, r, 1.3888888888888889e-03);
    p = fma(p, r, 8.3333333333333332e-03);
    p = fma(p, r, 4.1666666666666664e-02);
    p = fma(p, r, 1.6666666666666666e-01);
    p = fma(p, r, 0.5);
    p = fma(p, r, 1.0);
    p = fma(p, r, 1.0);
    long long bits = __double_as_longlong(p) + ((long long)(int)fn << 52);
    return __longlong_as_double(bits);
}
__device__ __forceinline__ double sig64f (double x){ return 1.0/(1.0 + fexp64(-x)); }
__device__ __forceinline__ double tanh64f(double x){ return 1.0 - 2.0/(fexp64(2.0*x) + 1.0); }

// XG precompute in f64; emit packed-hi [n][64][8] (+ optional residual [n][64][6]).
__global__ __launch_bounds__(384) void xg_kernel(const float* __restrict__ A,
    const float* __restrict__ W, const float* __restrict__ b,
    float* __restrict__ hiP, float* __restrict__ loP)
{
    __shared__ float a_s[8][64];
    const int g  = threadIdx.x;        // 0..383
    const int l  = g & 63, q = g >> 6;
    const int n0 = blockIdx.x * 8;
    for (int idx = threadIdx.x; idx < 8*64; idx += 384)
        a_s[idx>>6][idx&63] = A[(size_t)n0*64 + idx];
    __syncthreads();
    double acc[8];
    const double bg = (double)b[g];
#pragma unroll
    for (int j=0;j<8;j++) acc[j] = bg;
    for (int c=0;c<64;c++){
        const double w = (double)W[c*G3 + g];
#pragma unroll
        for (int j=0;j<8;j++) acc[j] += (double)a_s[j][c]*w;
    }
#pragma unroll
    for (int j=0;j<8;j++){
        const size_t base = (size_t)(n0+j)*64 + l;
        const float hi = (float)acc[j];
        hiP[base*8 + q] = hi;
        if (q < 2) hiP[base*8 + 6 + q] = 0.f;       // zero pad slots
        if (loP) loP[base*6 + q] = (float)(acc[j] - (double)hi);
    }
}

// Repack Wh [k][384] -> [k][lane][8] (slot m = W[k][64*m+lane], slots 6,7 = 0).
__global__ __launch_bounds__(256) void repack_kernel(const float* __restrict__ W,
                                                     float* __restrict__ P)
{
    const int idx = blockIdx.x*256 + threadIdx.x;   // 0 .. 128*512-1
    const int k = idx >> 9, rem = idx & 511, l = rem >> 3, s = rem & 7;
    P[idx] = (s < 6) ? W[k*G3 + s*64 + l] : 0.f;
}

// Phase 1: pure-f32 walk (r13 structure, passing). Records the FULL 4-bit
// trip mask per node (r15) so the fix can skip re-certified steps.
__global__ __launch_bounds__(256) void walk_kernel(
    const int*   __restrict__ nbrs,  const float* __restrict__ noise,
    const float* __restrict__ XGfP,  const float* __restrict__ dWhP,
    const float* __restrict__ dbh,   const float* __restrict__ dWo,
    const float* __restrict__ dbo,
    int* __restrict__ paths, int* __restrict__ fail_cnt, int* __restrict__ fail_list,
    float* __restrict__ out)
{
    __shared__ float hf_s[4][HD];
    __shared__ float part_s[4][4][6][64];

    const int wid  = threadIdx.x >> 6;
    const int lane = threadIdx.x & 63;
    const int node = blockIdx.x*4 + wid;

    float h0 = 0.f, h1 = 0.f;
    float dbhf[6], hgf[6];
#pragma unroll
    for (int m=0;m<6;m++){ dbhf[m] = dbh[lane+64*m]; hgf[m] = dbhf[m]; }
    const float wo0f0 = dWo[lane*CD];
    const float wo0f1 = dWo[(lane+64)*CD];
    const float dbo0f = dbo[0];

    int cur = node;
    int ch0=0, ch1=0, ch2=0, ch3=0;
    int tripmask = 0;

    for (int t=0;t<TT;t++){
        if      (t==0) ch0 = cur;
        else if (t==1) ch1 = cur;
        else if (t==2) ch2 = cur;
        else           ch3 = cur;

        // ---- extend prefix (packed row: 2 x b128) ----
        {
            const float4* xr = (const float4*)(XGfP + ((size_t)cur*64 + lane)*8);
            const float4 A = xr[0], B = xr[1];
            float r = fsig (A.x + hgf[0]);
            float z = fsig (A.z + hgf[2]);
            float n = ftanh(B.x + r*hgf[4]);
            h0 = (1.f-z)*n + z*h0;
            r = fsig (A.y + hgf[1]);
            z = fsig (A.w + hgf[3]);
            n = ftanh(B.y + r*hgf[5]);
            h1 = (1.f-z)*n + z*h1;
        }
        hf_s[wid][lane] = h0;  hf_s[wid][lane+64] = h1;
        __syncthreads();

        // ---- cooperative matvec: wave wid covers k = 32*wid .. 32*wid+31 ----
        {
            float pacc[4][6];
#pragma unroll
            for (int j=0;j<4;j++)
#pragma unroll
                for (int m=0;m<6;m++) pacc[j][m] = 0.f;
            const float4* wr = (const float4*)(dWhP + (size_t)lane*8);
#pragma unroll 4
            for (int kk=0; kk<32; kk++){
                const int k = wid*32 + kk;
                const float4 W0 = wr[k*128], W1 = wr[k*128+1];
#pragma unroll
                for (int j=0;j<4;j++){
                    const float hk = hf_s[j][k];
                    pacc[j][0] += hk*W0.x; pacc[j][1] += hk*W0.y;
                    pacc[j][2] += hk*W0.z; pacc[j][3] += hk*W0.w;
                    pacc[j][4] += hk*W1.x; pacc[j][5] += hk*W1.y;
                }
            }
#pragma unroll
            for (int j=0;j<4;j++)
#pragma unroll
                for (int m=0;m<6;m++) part_s[wid][j][m][lane] = pacc[j][m];
        }
        __syncthreads();

#pragma unroll
        for (int m=0;m<6;m++)
            hgf[m] = dbhf[m] + part_s[0][wid][m][lane] + part_s[1][wid][m][lane]
                             + part_s[2][wid][m][lane] + part_s[3][wid][m][lane];

        // ---- 16 candidates, per-wave ----
        int   nbrv = (lane < DG) ? nbrs[(size_t)cur*DG + lane] : 0;
        float nz   = (lane < DG) ? noise[((size_t)t*NN + node)*DG + lane] : 0.f;
        float lf = -3.0e38f;
#pragma unroll
        for (int g=0; g<4; g++){
            float4 CA[4], CB[4];
#pragma unroll
            for (int j=0;j<4;j++){
                const int nd = __shfl(nbrv, g*4+j);
                const float4* cr = (const float4*)(XGfP + ((size_t)nd*64 + lane)*8);
                CA[j] = cr[0];  CB[j] = cr[1];
            }
            float part[4];
#pragma unroll
            for (int j=0;j<4;j++){
                float r = fsig (CA[j].x + hgf[0]);
                float z = fsig (CA[j].z + hgf[2]);
                float n = ftanh(CB[j].x + r*hgf[4]);
                part[j]  = ((1.f-z)*n + z*h0) * wo0f0;
                r = fsig (CA[j].y + hgf[1]);
                z = fsig (CA[j].w + hgf[3]);
                n = ftanh(CB[j].y + r*hgf[5]);
                part[j] += ((1.f-z)*n + z*h1) * wo0f1;
            }
#pragma unroll
            for (int off=32; off>0; off>>=1){
#pragma unroll
                for (int j=0;j<4;j++) part[j] += __shfl_xor(part[j], off);
            }
#pragma unroll
            for (int j=0;j<4;j++) if (lane == g*4+j) lf = part[j] + dbo0f;
        }

        // ---- softmax + noisy argmax + top-2 margin ----
        float v  = (lane < DG) ? lf : -3.0e38f;
        float mx = v;
#pragma unroll
        for (int off=32; off>0; off>>=1) mx = fmaxf(mx, __shfl_xor(mx, off));
        float e = (lane < DG) ? __expf(v - mx) : 0.f;
        float s = e;
#pragma unroll
        for (int off=32; off>0; off>>=1) s += __shfl_xor(s, off);
        const float normf = mx + __logf(s);

        float noisyf = (lane < DG) ? __expf(v - normf) + 0.01f*nz : -3.0e38f;
        int   idx = lane;
        float bv  = noisyf;
#pragma unroll
        for (int off=32; off>0; off>>=1){
            float ov = __shfl_xor(bv, off);
            int   oi = __shfl_xor(idx, off);
            if (ov > bv || (ov == bv && oi < idx)){ bv = ov; idx = oi; }
        }
        float sv = (lane == idx || lane >= DG) ? -3.0e38f : noisyf;
#pragma unroll
        for (int off=32; off>0; off>>=1) sv = fmaxf(sv, __shfl_xor(sv, off));

        if ((bv - sv) < MARGIN) tripmask |= (1 << t);   // wave-uniform

        const float lpf = __shfl(v, idx) - normf;
        if (lane == 0) out[NN*CD + node*TT + t] = lpf;
        cur = __shfl(nbrv, idx);
    }

    if (lane == 0){
        int* p = paths + (size_t)node*8;
        p[0]=ch0; p[1]=ch1; p[2]=ch2; p[3]=ch3; p[4]=cur;
        if (tripmask){
            const int slot = atomicAdd(fail_cnt, 1);
            if (slot < NN) fail_list[slot] = node | (tripmask << 16);
        }
    }
}

// Phase 2: exact-f64 redo (standalone, r13 structure + r15 refinements):
//  - 28KB LDS via 3-stage pairwise reduction of the coop-f64-matvec partials
//    (occupancy 3 -> 5 blocks/CU).
//  - trip-MASK selective scoring: score step t only if (mask bit t set) OR
//    (f64 trajectory has diverged from walk's recorded path). Re-confirmed
//    trips keep later certificates valid (same induction as the prefix skip).
__global__ __launch_bounds__(256) void fix_kernel(
    const int*   __restrict__ nbrs,  const float* __restrict__ noise,
    const float* __restrict__ XGfP,  const float* __restrict__ XGrP,
    const float* __restrict__ dWhP,  const float* __restrict__ dbh,
    const float* __restrict__ dWo,   const float* __restrict__ dbo,
    const int* __restrict__ fail_cnt, const int* __restrict__ fail_list,
    int* __restrict__ paths, float* __restrict__ out)
{
    __shared__ double smem[3584];            // 28672 B: h_s[512] + dbuf[3072]
    double* h_s  = smem;                     // [4][HD]
    double* dbuf = smem + 512;               // [2][4][6][64]

    const int wid  = threadIdx.x >> 6;
    const int lane = threadIdx.x & 63;
    const int count = min(fail_cnt[0], NN);
    if (blockIdx.x*4 >= count) return;       // whole-block early exit (uniform)

    const int  ii     = blockIdx.x*4 + wid;
    const bool active = (ii < count);
    const int  entry  = active ? fail_list[ii] : 0;   // idle waves ride node 0
    const int  node   = entry & 0xFFFF;
    const int  mask   = active ? (entry >> 16) : 0;   // idle: never score
    const int* pw     = paths + (size_t)node*8;

    double db64[6];
#pragma unroll
    for (int m=0;m<6;m++) db64[m] = (double)dbh[lane+64*m];
    const double wo0d0 = (double)dWo[lane*CD];
    const double wo0d1 = (double)dWo[(lane+64)*CD];
    const double dbo0d = (double)dbo[0];

    double H0 = 0.0, H1 = 0.0;
    double g64[6];
#pragma unroll
    for (int m=0;m<6;m++) g64[m] = db64[m];
    int  cur = node;
    int  c0=0,c1=0,c2=0,c3=0;
    bool diverged = false;

    for (int t=0;t<TT;t++){
        if      (t==0) c0 = cur;
        else if (t==1) c1 = cur;
        else if (t==2) c2 = cur;
        else           c3 = cur;

        // ---- extend (f64 = hi + residual) ----
        {
            const size_t b = (size_t)cur*64 + lane;
            const float* hi = XGfP + b*8;
            const float* lo = XGrP + b*6;
            double r = sig64f (((double)hi[0]+(double)lo[0]) + g64[0]);
            double z = sig64f (((double)hi[2]+(double)lo[2]) + g64[2]);
            double n = tanh64f(((double)hi[4]+(double)lo[4]) + r*g64[4]);
            H0 = (1.0-z)*n + z*H0;
            r = sig64f (((double)hi[1]+(double)lo[1]) + g64[1]);
            z = sig64f (((double)hi[3]+(double)lo[3]) + g64[3]);
            n = tanh64f(((double)hi[5]+(double)lo[5]) + r*g64[5]);
            H1 = (1.0-z)*n + z*H1;
        }
        h_s[wid*HD + lane] = H0;  h_s[wid*HD + lane + 64] = H1;
        __syncthreads();                            // (1) h ready

        // ---- cooperative f64 matvec, 3-stage pairwise reduction (28KB) ----
        double pacc[4][6];
#pragma unroll
        for (int j=0;j<4;j++)
#pragma unroll
            for (int m=0;m<6;m++) pacc[j][m] = 0.0;
        {
            const float4* wv = (const float4*)(dWhP + (size_t)lane*8);
#pragma unroll 4
            for (int kk=0; kk<32; kk++){
                const int k = wid*32 + kk;
                const float4 W0 = wv[k*128], W1 = wv[k*128+1];
#pragma unroll
                for (int j=0;j<4;j++){
                    const double hk = h_s[j*HD + k];
                    pacc[j][0] += hk*(double)W0.x; pacc[j][1] += hk*(double)W0.y;
                    pacc[j][2] += hk*(double)W0.z; pacc[j][3] += hk*(double)W0.w;
                    pacc[j][4] += hk*(double)W1.x; pacc[j][5] += hk*(double)W1.y;
                }
            }
        }
        if (wid >= 2){
#pragma unroll
            for (int j=0;j<4;j++)
#pragma unroll
                for (int m=0;m<6;m++)
                    dbuf[(((wid-2)*4+j)*6+m)*64 + lane] = pacc[j][m];
        }
        __syncthreads();                            // (2) writers 2,3 published
        if (wid < 2){
#pragma unroll
            for (int j=0;j<4;j++)
#pragma unroll
                for (int m=0;m<6;m++){
                    pacc[j][m] += dbuf[((wid*4+j)*6+m)*64 + lane];
                    dbuf[((wid*4+j)*6+m)*64 + lane] = pacc[j][m];
                }
        }
        __syncthreads();                            // (3) pair sums published
#pragma unroll
        for (int m=0;m<6;m++)
            g64[m] = db64[m] + dbuf[((0*4+wid)*6+m)*64 + lane]
                             + dbuf[((1*4+wid)*6+m)*64 + lane];

        // ---- certified step (not tripped, on recorded path): skip scoring ----
        if (!diverged && !((mask >> t) & 1)){
            cur = pw[t+1];
            continue;                               // no barriers below — safe
        }

        // ---- 16 candidates f64, 4 groups of 4 with prefetch ----
        int   nbrv = (lane < DG) ? nbrs[(size_t)cur*DG + lane] : 0;
        float nz   = (lane < DG) ? noise[((size_t)t*NN + node)*DG + lane] : 0.f;
        double lv = -1e300;
#pragma unroll
        for (int g=0; g<4; g++){
            float ch[4][6], cl[4][6];
#pragma unroll
            for (int j=0;j<4;j++){
                const int nd = __shfl(nbrv, g*4+j);
                const size_t b = (size_t)nd*64 + lane;
                const float* hi = XGfP + b*8;
                const float* lo = XGrP + b*6;
#pragma unroll
                for (int q=0;q<6;q++){ ch[j][q]=hi[q]; cl[j][q]=lo[q]; }
            }
#pragma unroll
            for (int j=0;j<4;j++){
                double r = sig64f (((double)ch[j][0]+(double)cl[j][0]) + g64[0]);
                double z = sig64f (((double)ch[j][2]+(double)cl[j][2]) + g64[2]);
                double n = tanh64f(((double)ch[j][4]+(double)cl[j][4]) + r*g64[4]);
                double part = ((1.0-z)*n + z*H0) * wo0d0;
                r = sig64f (((double)ch[j][1]+(double)cl[j][1]) + g64[1]);
                z = sig64f (((double)ch[j][3]+(double)cl[j][3]) + g64[3]);
                n = tanh64f(((double)ch[j][5]+(double)cl[j][5]) + r*g64[5]);
                part += ((1.0-z)*n + z*H1) * wo0d1;
#pragma unroll
                for (int off=32; off>0; off>>=1) part += __shfl_xor(part, off);
                if (lane == g*4+j) lv = part + dbo0d;
            }
        }

        // ---- softmax + noisy argmax (identical numerics to r9-r14) ----
        double dv = (lane < DG) ? lv : -1e300;
        double dmx = dv;
#pragma unroll
        for (int off=32; off>0; off>>=1) dmx = fmax(dmx, __shfl_xor(dmx, off));
        double de = (lane < DG) ? fexp64(dv - dmx) : 0.0;
        double ds = de;
#pragma unroll
        for (int off=32; off>0; off>>=1) ds += __shfl_xor(ds, off);
        const double dnorm = dmx + log(ds);
        double dnoisy = (lane < DG) ? fexp64(dv - dnorm) + 0.01*(double)nz : -1e300;
        int di = lane;
#pragma unroll
        for (int off=32; off>0; off>>=1){
            double ov = __shfl_xor(dnoisy, off);
            int    oi = __shfl_xor(di, off);
            if (ov > dnoisy || (ov == dnoisy && oi < di)){ dnoisy = ov; di = oi; }
        }
        const double lpfix = __shfl(dv, di) - dnorm;
        if (active && lane == 0) out[NN*CD + node*TT + t] = (float)lpfix;
        const int newcur = __shfl(nbrv, di);
        diverged = diverged || (newcur != pw[t+1]);
        cur = newcur;
    }

    if (active && lane == 0){
        int* p = paths + (size_t)node*8;
        p[0]=c0; p[1]=c1; p[2]=c2; p[3]=c3; p[4]=cur;
    }
}

// w-GRU over the recorded 5-node walk; block-cooperative matvec (r11/r13).
__global__ __launch_bounds__(256) void wgru_kernel(
    const int*   __restrict__ paths, const float* __restrict__ XGwP,
    const float* __restrict__ wWhP,  const float* __restrict__ wbh,
    const float* __restrict__ wWo,   const float* __restrict__ wbo,
    float* __restrict__ out)
{
    __shared__ float hw_s[4][HD];
    __shared__ float part_s[4][4][6][64];
    const int wid  = threadIdx.x >> 6;
    const int lane = threadIdx.x & 63;
    const int node = blockIdx.x*4 + wid;

    float h0 = 0.f, h1 = 0.f;
    float wb[6], hg[6];
#pragma unroll
    for (int m=0;m<6;m++){ wb[m] = wbh[lane+64*m]; hg[m] = wb[m]; }
    const int* p = paths + (size_t)node*8;

#pragma unroll
    for (int s=0; s<=TT; s++){
        const int c = p[s];
        const float4* xr = (const float4*)(XGwP + ((size_t)c*64 + lane)*8);
        const float4 A = xr[0], B = xr[1];
        float r = fsig (A.x + hg[0]);
        float z = fsig (A.z + hg[2]);
        float n = ftanh(B.x + r*hg[4]);
        h0 = (1.f-z)*n + z*h0;
        r = fsig (A.y + hg[1]);
        z = fsig (A.w + hg[3]);
        n = ftanh(B.y + r*hg[5]);
        h1 = (1.f-z)*n + z*h1;
        if (s < TT){
            hw_s[wid][lane] = h0;  hw_s[wid][lane+64] = h1;
            __syncthreads();
            float pacc[4][6];
#pragma unroll
            for (int j=0;j<4;j++)
#pragma unroll
                for (int m=0;m<6;m++) pacc[j][m] = 0.f;
            const float4* wr = (const float4*)(wWhP + (size_t)lane*8);
#pragma unroll 4
            for (int kk=0; kk<32; kk++){
                const int k = wid*32 + kk;
                const float4 W0 = wr[k*128], W1 = wr[k*128+1];
#pragma unroll
                for (int j=0;j<4;j++){
                    const float hk = hw_s[j][k];
                    pacc[j][0] += hk*W0.x; pacc[j][1] += hk*W0.y;
                    pacc[j][2] += hk*W0.z; pacc[j][3] += hk*W0.w;
                    pacc[j][4] += hk*W1.x; pacc[j][5] += hk*W1.y;
                }
            }
#pragma unroll
            for (int j=0;j<4;j++)
#pragma unroll
                for (int m=0;m<6;m++) part_s[wid][j][m][lane] = pacc[j][m];
            __syncthreads();
#pragma unroll
            for (int m=0;m<6;m++)
                hg[m] = wb[m] + part_s[0][wid][m][lane] + part_s[1][wid][m][lane]
                              + part_s[2][wid][m][lane] + part_s[3][wid][m][lane];
        }
    }
    hw_s[wid][lane] = h0;  hw_s[wid][lane+64] = h1;
    __syncthreads();

    float acc = wbo[lane];                 // CD == 64 == wave width
    const float* wcol = wWo + lane;
    for (int i=0;i<HD;i++) acc += hw_s[wid][i] * wcol[(size_t)i*CD];
    out[(size_t)node*CD + lane] = acc;
}

extern "C" void kernel_launch(void* const* d_in, const int* in_sizes, int n_in,
                              void* d_out, int out_size, void* d_ws, size_t ws_size,
                              hipStream_t stream)
{
    const float* attr  = (const float*)d_in[0];
    const int*   nbrs  = (const int*)  d_in[1];
    const float* noise = (const float*)d_in[2];
    const float* dWx = (const float*)d_in[3];
    const float* dWh = (const float*)d_in[4];
    const float* dbx = (const float*)d_in[5];
    const float* dbh = (const float*)d_in[6];
    const float* dWo = (const float*)d_in[7];
    const float* dbo = (const float*)d_in[8];
    const float* wWx = (const float*)d_in[9];
    const float* wWh = (const float*)d_in[10];
    const float* wbx = (const float*)d_in[11];
    const float* wbh = (const float*)d_in[12];
    const float* wWo = (const float*)d_in[13];
    const float* wbo = (const float*)d_in[14];
    float* out = (float*)d_out;

    char* ws = (char*)d_ws;
    float* XGfP      = (float*)(ws);                 // 16,384,000 B
    float* XGrP      = (float*)(ws + 16384000);      // 12,288,000 B
    float* XGwP      = (float*)(ws + 28672000);      // 16,384,000 B
    float* dWhP      = (float*)(ws + 45056000);      // 262,144 B
    float* wWhP      = (float*)(ws + 45318144);      // 262,144 B
    int*   paths     = (int*)  (ws + 45580288);      // 256,000 B
    int*   fail_list = (int*)  (ws + 45836288);      // 32,000 B
    int*   fail_cnt  = (int*)  (ws + 45868288);      // 4 B  (total ~45.9 MB)

    hipMemsetAsync(fail_cnt, 0, sizeof(int), stream);

    xg_kernel<<<NN/8, G3, 0, stream>>>(attr, dWx, dbx, XGfP, XGrP);
    xg_kernel<<<NN/8, G3, 0, stream>>>(attr, wWx, wbx, XGwP, nullptr);
    repack_kernel<<<(HD*64*8)/256, 256, 0, stream>>>(dWh, dWhP);
    repack_kernel<<<(HD*64*8)/256, 256, 0, stream>>>(wWh, wWhP);

    walk_kernel<<<NN/4, 256, 0, stream>>>(nbrs, noise, XGfP, dWhP,
                                          dbh, dWo, dbo,
                                          paths, fail_cnt, fail_list, out);
    fix_kernel<<<2000, 256, 0, stream>>>(nbrs, noise, XGfP, XGrP,
                                         dWhP, dbh, dWo, dbo,
                                         fail_cnt, fail_list, paths, out);
    wgru_kernel<<<NN/4, 256, 0, stream>>>(paths, XGwP, wWhP, wbh, wWo, wbo, out);
}

// Round 16
// 493.031 us; speedup vs baseline: 1.0997x; 1.0654x over previous
//
#include <hip/hip_runtime.h>
#include <math.h>

#define NN 8000   // nodes
#define CD 64     // node feature dim / C_OUT
#define DG 16     // neighbors per node
#define HD 128    // GRU hidden
#define G3 384    // 3*HD
#define TT 4      // walk steps
// Worst-case f32 noisy-score error bound ~1e-3; MARGIN = 4e-3 (proven r8-r15).
#define MARGIN 4e-3f

#if __has_builtin(__builtin_amdgcn_rcpf)
#define RCP(x) __builtin_amdgcn_rcpf(x)
#else
#define RCP(x) (1.f/(x))
#endif

// fast f32 (walk + wgru; error ~1e-6 << MARGIN)
__device__ __forceinline__ float fsig (float x){ return RCP(1.f + __expf(-x)); }
__device__ __forceinline__ float ftanh(float x){ return 1.f - 2.f*RCP(1.f + __expf(2.f*x)); }

// fast f64 exp: range-reduced 13-term Horner, ~3 ulp (validated r9-r15).
__device__ __forceinline__ double fexp64(double x){
    const double LOG2E  = 1.4426950408889634074;
    const double LN2_HI = 6.93147180369123816490e-01;
    const double LN2_LO = 1.90821492927058770002e-10;
    x = fmin(fmax(x, -700.0), 700.0);
    double fn = rint(x * LOG2E);
    double r  = fma(-fn, LN2_HI, x);
    r = fma(-fn, LN2_LO, r);
    double p = 1.6059043836821613e-10;            // 1/13!
    p = fma(p, r, 2.0876756987868099e-09);
    p = fma(p, r, 2.5052108385441719e-08);
    p = fma(p, r, 2.7557319223985893e-07);
    p = fma(p, r, 2.7557319223985888e-06);
    p = fma(p, r, 2.4801587301587302e-05);
    p = fma(p, r, 1.9841269841269841e-04);
    p = fma(p, r, 1.3888888888888889e-03);
    p = fma(p, r, 8.3333333333333332e-03);
    p = fma(p, r, 4.1666666666666664e-02);
    p = fma(p, r, 1.6666666666666666e-01);
    p = fma(p, r, 0.5);
    p = fma(p, r, 1.0);
    p = fma(p, r, 1.0);
    long long bits = __double_as_longlong(p) + ((long long)(int)fn << 52);
    return __longlong_as_double(bits);
}
__device__ __forceinline__ double sig64f (double x){ return 1.0/(1.0 + fexp64(-x)); }
__device__ __forceinline__ double tanh64f(double x){ return 1.0 - 2.0/(fexp64(2.0*x) + 1.0); }

// XG precompute in f64; emit packed-hi [n][64][8] (+ optional residual [n][64][6]).
__global__ __launch_bounds__(384) void xg_kernel(const float* __restrict__ A,
    const float* __restrict__ W, const float* __restrict__ b,
    float* __restrict__ hiP, float* __restrict__ loP)
{
    __shared__ float a_s[8][64];
    const int g  = threadIdx.x;        // 0..383
    const int l  = g & 63, q = g >> 6;
    const int n0 = blockIdx.x * 8;
    for (int idx = threadIdx.x; idx < 8*64; idx += 384)
        a_s[idx>>6][idx&63] = A[(size_t)n0*64 + idx];
    __syncthreads();
    double acc[8];
    const double bg = (double)b[g];
#pragma unroll
    for (int j=0;j<8;j++) acc[j] = bg;
    for (int c=0;c<64;c++){
        const double w = (double)W[c*G3 + g];
#pragma unroll
        for (int j=0;j<8;j++) acc[j] += (double)a_s[j][c]*w;
    }
#pragma unroll
    for (int j=0;j<8;j++){
        const size_t base = (size_t)(n0+j)*64 + l;
        const float hi = (float)acc[j];
        hiP[base*8 + q] = hi;
        if (q < 2) hiP[base*8 + 6 + q] = 0.f;       // zero pad slots
        if (loP) loP[base*6 + q] = (float)(acc[j] - (double)hi);
    }
}

// Repack Wh [k][384] -> [k][lane][8] (slot m = W[k][64*m+lane], slots 6,7 = 0).
__global__ __launch_bounds__(256) void repack_kernel(const float* __restrict__ W,
                                                     float* __restrict__ P)
{
    const int idx = blockIdx.x*256 + threadIdx.x;   // 0 .. 128*512-1
    const int k = idx >> 9, rem = idx & 511, l = rem >> 3, s = rem & 7;
    P[idx] = (s < 6) ? W[k*G3 + s*64 + l] : 0.f;
}

// Phase 1: pure-f32 walk (r13 structure). Records the 4-bit trip mask per
// node, binned by LAST tripped step (r16) so fix blocks get uniform replay
// lengths and can early-break.
__global__ __launch_bounds__(256) void walk_kernel(
    const int*   __restrict__ nbrs,  const float* __restrict__ noise,
    const float* __restrict__ XGfP,  const float* __restrict__ dWhP,
    const float* __restrict__ dbh,   const float* __restrict__ dWo,
    const float* __restrict__ dbo,
    int* __restrict__ paths, int* __restrict__ fail_cnt, int* __restrict__ fail_list,
    float* __restrict__ out)
{
    __shared__ float hf_s[4][HD];
    __shared__ float part_s[4][4][6][64];

    const int wid  = threadIdx.x >> 6;
    const int lane = threadIdx.x & 63;
    const int node = blockIdx.x*4 + wid;

    float h0 = 0.f, h1 = 0.f;
    float dbhf[6], hgf[6];
#pragma unroll
    for (int m=0;m<6;m++){ dbhf[m] = dbh[lane+64*m]; hgf[m] = dbhf[m]; }
    const float wo0f0 = dWo[lane*CD];
    const float wo0f1 = dWo[(lane+64)*CD];
    const float dbo0f = dbo[0];

    int cur = node;
    int ch0=0, ch1=0, ch2=0, ch3=0;
    int tripmask = 0;

    for (int t=0;t<TT;t++){
        if      (t==0) ch0 = cur;
        else if (t==1) ch1 = cur;
        else if (t==2) ch2 = cur;
        else           ch3 = cur;

        // ---- extend prefix (packed row: 2 x b128) ----
        {
            const float4* xr = (const float4*)(XGfP + ((size_t)cur*64 + lane)*8);
            const float4 A = xr[0], B = xr[1];
            float r = fsig (A.x + hgf[0]);
            float z = fsig (A.z + hgf[2]);
            float n = ftanh(B.x + r*hgf[4]);
            h0 = (1.f-z)*n + z*h0;
            r = fsig (A.y + hgf[1]);
            z = fsig (A.w + hgf[3]);
            n = ftanh(B.y + r*hgf[5]);
            h1 = (1.f-z)*n + z*h1;
        }
        hf_s[wid][lane] = h0;  hf_s[wid][lane+64] = h1;
        __syncthreads();

        // ---- cooperative matvec: wave wid covers k = 32*wid .. 32*wid+31 ----
        {
            float pacc[4][6];
#pragma unroll
            for (int j=0;j<4;j++)
#pragma unroll
                for (int m=0;m<6;m++) pacc[j][m] = 0.f;
            const float4* wr = (const float4*)(dWhP + (size_t)lane*8);
#pragma unroll 4
            for (int kk=0; kk<32; kk++){
                const int k = wid*32 + kk;
                const float4 W0 = wr[k*128], W1 = wr[k*128+1];
#pragma unroll
                for (int j=0;j<4;j++){
                    const float hk = hf_s[j][k];
                    pacc[j][0] += hk*W0.x; pacc[j][1] += hk*W0.y;
                    pacc[j][2] += hk*W0.z; pacc[j][3] += hk*W0.w;
                    pacc[j][4] += hk*W1.x; pacc[j][5] += hk*W1.y;
                }
            }
#pragma unroll
            for (int j=0;j<4;j++)
#pragma unroll
                for (int m=0;m<6;m++) part_s[wid][j][m][lane] = pacc[j][m];
        }
        __syncthreads();

#pragma unroll
        for (int m=0;m<6;m++)
            hgf[m] = dbhf[m] + part_s[0][wid][m][lane] + part_s[1][wid][m][lane]
                             + part_s[2][wid][m][lane] + part_s[3][wid][m][lane];

        // ---- 16 candidates, per-wave ----
        int   nbrv = (lane < DG) ? nbrs[(size_t)cur*DG + lane] : 0;
        float nz   = (lane < DG) ? noise[((size_t)t*NN + node)*DG + lane] : 0.f;
        float lf = -3.0e38f;
#pragma unroll
        for (int g=0; g<4; g++){
            float4 CA[4], CB[4];
#pragma unroll
            for (int j=0;j<4;j++){
                const int nd = __shfl(nbrv, g*4+j);
                const float4* cr = (const float4*)(XGfP + ((size_t)nd*64 + lane)*8);
                CA[j] = cr[0];  CB[j] = cr[1];
            }
            float part[4];
#pragma unroll
            for (int j=0;j<4;j++){
                float r = fsig (CA[j].x + hgf[0]);
                float z = fsig (CA[j].z + hgf[2]);
                float n = ftanh(CB[j].x + r*hgf[4]);
                part[j]  = ((1.f-z)*n + z*h0) * wo0f0;
                r = fsig (CA[j].y + hgf[1]);
                z = fsig (CA[j].w + hgf[3]);
                n = ftanh(CB[j].y + r*hgf[5]);
                part[j] += ((1.f-z)*n + z*h1) * wo0f1;
            }
#pragma unroll
            for (int off=32; off>0; off>>=1){
#pragma unroll
                for (int j=0;j<4;j++) part[j] += __shfl_xor(part[j], off);
            }
#pragma unroll
            for (int j=0;j<4;j++) if (lane == g*4+j) lf = part[j] + dbo0f;
        }

        // ---- softmax + noisy argmax + top-2 margin ----
        float v  = (lane < DG) ? lf : -3.0e38f;
        float mx = v;
#pragma unroll
        for (int off=32; off>0; off>>=1) mx = fmaxf(mx, __shfl_xor(mx, off));
        float e = (lane < DG) ? __expf(v - mx) : 0.f;
        float s = e;
#pragma unroll
        for (int off=32; off>0; off>>=1) s += __shfl_xor(s, off);
        const float normf = mx + __logf(s);

        float noisyf = (lane < DG) ? __expf(v - normf) + 0.01f*nz : -3.0e38f;
        int   idx = lane;
        float bv  = noisyf;
#pragma unroll
        for (int off=32; off>0; off>>=1){
            float ov = __shfl_xor(bv, off);
            int   oi = __shfl_xor(idx, off);
            if (ov > bv || (ov == bv && oi < idx)){ bv = ov; idx = oi; }
        }
        float sv = (lane == idx || lane >= DG) ? -3.0e38f : noisyf;
#pragma unroll
        for (int off=32; off>0; off>>=1) sv = fmaxf(sv, __shfl_xor(sv, off));

        if ((bv - sv) < MARGIN) tripmask |= (1 << t);   // wave-uniform

        const float lpf = __shfl(v, idx) - normf;
        if (lane == 0) out[NN*CD + node*TT + t] = lpf;
        cur = __shfl(nbrv, idx);
    }

    if (lane == 0){
        int* p = paths + (size_t)node*8;
        p[0]=ch0; p[1]=ch1; p[2]=ch2; p[3]=ch3; p[4]=cur;
        if (tripmask){
            const int bin = 31 - __clz(tripmask);   // last tripped step 0..3
            const int slot = atomicAdd(&fail_cnt[bin], 1);
            fail_list[bin*NN + slot] = node | (tripmask << 16);
        }
    }
}

// Phase 2: exact-f64 redo (r15 structure + r16 early termination):
//  - entries binned by last-tripped-step -> block's 4 waves share replay len.
//  - per-wave done flag (no remaining mask bits, not diverged): skips extend
//    gathers + fexp64 (stale h_s feeds only its own never-read partials).
//  - block-uniform break via __syncthreads_and once all 4 waves are done.
// All computed f64 values are bit-identical to r15 — only dead work elided.
__global__ __launch_bounds__(256) void fix_kernel(
    const int*   __restrict__ nbrs,  const float* __restrict__ noise,
    const float* __restrict__ XGfP,  const float* __restrict__ XGrP,
    const float* __restrict__ dWhP,  const float* __restrict__ dbh,
    const float* __restrict__ dWo,   const float* __restrict__ dbo,
    const int* __restrict__ fail_cnt, const int* __restrict__ fail_list,
    int* __restrict__ paths, float* __restrict__ out)
{
    __shared__ double smem[3584];            // 28672 B: h_s[512] + dbuf[3072]
    double* h_s  = smem;                     // [4][HD]
    double* dbuf = smem + 512;               // [2][4][6][64]

    const int wid  = threadIdx.x >> 6;
    const int lane = threadIdx.x & 63;
    const int n0c = fail_cnt[0], n1c = fail_cnt[1], n2c = fail_cnt[2], n3c = fail_cnt[3];
    const int total = n0c + n1c + n2c + n3c;
    if (blockIdx.x*4 >= total) return;       // whole-block early exit (uniform)

    const int  ii     = blockIdx.x*4 + wid;
    const bool active = (ii < total);
    int entry = 0;
    if (active){
        int b, loc;
        if      (ii < n0c)            { b=0; loc=ii; }
        else if (ii < n0c+n1c)        { b=1; loc=ii-n0c; }
        else if (ii < n0c+n1c+n2c)    { b=2; loc=ii-n0c-n1c; }
        else                          { b=3; loc=ii-n0c-n1c-n2c; }
        entry = fail_list[b*NN + loc];
    }
    const int  node = entry & 0xFFFF;
    const int  mask = active ? (entry >> 16) : 0;   // idle: done immediately
    const int* pw   = paths + (size_t)node*8;

    double db64[6];
#pragma unroll
    for (int m=0;m<6;m++) db64[m] = (double)dbh[lane+64*m];
    const double wo0d0 = (double)dWo[lane*CD];
    const double wo0d1 = (double)dWo[(lane+64)*CD];
    const double dbo0d = (double)dbo[0];

    double H0 = 0.0, H1 = 0.0;
    double g64[6];
#pragma unroll
    for (int m=0;m<6;m++) g64[m] = db64[m];
    int  cur = node;
    int  c0=0,c1=0,c2=0,c3=0;
    bool diverged = false;

    for (int t=0;t<TT;t++){
        // done: no remaining mask bits and still on the certified path
        const bool done = !diverged && ((mask >> t) == 0);
        if (__syncthreads_and(done ? 1 : 0)) break;   // block-uniform

        if      (t==0) c0 = cur;
        else if (t==1) c1 = cur;
        else if (t==2) c2 = cur;
        else           c3 = cur;

        // ---- extend (f64 = hi + residual); skipped for done waves ----
        if (!done){
            const size_t b = (size_t)cur*64 + lane;
            const float* hi = XGfP + b*8;
            const float* lo = XGrP + b*6;
            double r = sig64f (((double)hi[0]+(double)lo[0]) + g64[0]);
            double z = sig64f (((double)hi[2]+(double)lo[2]) + g64[2]);
            double n = tanh64f(((double)hi[4]+(double)lo[4]) + r*g64[4]);
            H0 = (1.0-z)*n + z*H0;
            r = sig64f (((double)hi[1]+(double)lo[1]) + g64[1]);
            z = sig64f (((double)hi[3]+(double)lo[3]) + g64[3]);
            n = tanh64f(((double)hi[5]+(double)lo[5]) + r*g64[5]);
            H1 = (1.0-z)*n + z*H1;
            h_s[wid*HD + lane] = H0;  h_s[wid*HD + lane + 64] = H1;
        }
        __syncthreads();                            // (1) h ready

        // ---- cooperative f64 matvec, 3-stage pairwise reduction (28KB) ----
        double pacc[4][6];
#pragma unroll
        for (int j=0;j<4;j++)
#pragma unroll
            for (int m=0;m<6;m++) pacc[j][m] = 0.0;
        {
            const float4* wv = (const float4*)(dWhP + (size_t)lane*8);
#pragma unroll 4
            for (int kk=0; kk<32; kk++){
                const int k = wid*32 + kk;
                const float4 W0 = wv[k*128], W1 = wv[k*128+1];
#pragma unroll
                for (int j=0;j<4;j++){
                    const double hk = h_s[j*HD + k];
                    pacc[j][0] += hk*(double)W0.x; pacc[j][1] += hk*(double)W0.y;
                    pacc[j][2] += hk*(double)W0.z; pacc[j][3] += hk*(double)W0.w;
                    pacc[j][4] += hk*(double)W1.x; pacc[j][5] += hk*(double)W1.y;
                }
            }
        }
        if (wid >= 2){
#pragma unroll
            for (int j=0;j<4;j++)
#pragma unroll
                for (int m=0;m<6;m++)
                    dbuf[(((wid-2)*4+j)*6+m)*64 + lane] = pacc[j][m];
        }
        __syncthreads();                            // (2) writers 2,3 published
        if (wid < 2){
#pragma unroll
            for (int j=0;j<4;j++)
#pragma unroll
                for (int m=0;m<6;m++){
                    pacc[j][m] += dbuf[((wid*4+j)*6+m)*64 + lane];
                    dbuf[((wid*4+j)*6+m)*64 + lane] = pacc[j][m];
                }
        }
        __syncthreads();                            // (3) pair sums published
        if (!done){
#pragma unroll
            for (int m=0;m<6;m++)
                g64[m] = db64[m] + dbuf[((0*4+wid)*6+m)*64 + lane]
                                 + dbuf[((1*4+wid)*6+m)*64 + lane];
        }

        // ---- certified step (not tripped, on recorded path): skip scoring ----
        if (!diverged && !((mask >> t) & 1)){
            cur = pw[t+1];
            continue;                               // no barriers below — safe
        }

        // ---- 16 candidates f64, 4 groups of 4 with prefetch ----
        int   nbrv = (lane < DG) ? nbrs[(size_t)cur*DG + lane] : 0;
        float nz   = (lane < DG) ? noise[((size_t)t*NN + node)*DG + lane] : 0.f;
        double lv = -1e300;
#pragma unroll
        for (int g=0; g<4; g++){
            float ch[4][6], cl[4][6];
#pragma unroll
            for (int j=0;j<4;j++){
                const int nd = __shfl(nbrv, g*4+j);
                const size_t b = (size_t)nd*64 + lane;
                const float* hi = XGfP + b*8;
                const float* lo = XGrP + b*6;
#pragma unroll
                for (int q=0;q<6;q++){ ch[j][q]=hi[q]; cl[j][q]=lo[q]; }
            }
#pragma unroll
            for (int j=0;j<4;j++){
                double r = sig64f (((double)ch[j][0]+(double)cl[j][0]) + g64[0]);
                double z = sig64f (((double)ch[j][2]+(double)cl[j][2]) + g64[2]);
                double n = tanh64f(((double)ch[j][4]+(double)cl[j][4]) + r*g64[4]);
                double part = ((1.0-z)*n + z*H0) * wo0d0;
                r = sig64f (((double)ch[j][1]+(double)cl[j][1]) + g64[1]);
                z = sig64f (((double)ch[j][3]+(double)cl[j][3]) + g64[3]);
                n = tanh64f(((double)ch[j][5]+(double)cl[j][5]) + r*g64[5]);
                part += ((1.0-z)*n + z*H1) * wo0d1;
#pragma unroll
                for (int off=32; off>0; off>>=1) part += __shfl_xor(part, off);
                if (lane == g*4+j) lv = part + dbo0d;
            }
        }

        // ---- softmax + noisy argmax (identical numerics to r9-r15) ----
        double dv = (lane < DG) ? lv : -1e300;
        double dmx = dv;
#pragma unroll
        for (int off=32; off>0; off>>=1) dmx = fmax(dmx, __shfl_xor(dmx, off));
        double de = (lane < DG) ? fexp64(dv - dmx) : 0.0;
        double ds = de;
#pragma unroll
        for (int off=32; off>0; off>>=1) ds += __shfl_xor(ds, off);
        const double dnorm = dmx + log(ds);
        double dnoisy = (lane < DG) ? fexp64(dv - dnorm) + 0.01*(double)nz : -1e300;
        int di = lane;
#pragma unroll
        for (int off=32; off>0; off>>=1){
            double ov = __shfl_xor(dnoisy, off);
            int    oi = __shfl_xor(di, off);
            if (ov > dnoisy || (ov == dnoisy && oi < di)){ dnoisy = ov; di = oi; }
        }
        const double lpfix = __shfl(dv, di) - dnorm;
        if (active && lane == 0) out[NN*CD + node*TT + t] = (float)lpfix;
        const int newcur = __shfl(nbrv, di);
        diverged = diverged || (newcur != pw[t+1]);
        cur = newcur;
    }

    // Path rewrite only needed when the trajectory actually changed; a
    // non-diverged node's recorded path is already exact.
    if (active && diverged && lane == 0){
        int* p = paths + (size_t)node*8;
        p[0]=c0; p[1]=c1; p[2]=c2; p[3]=c3; p[4]=cur;
    }
}

// w-GRU over the recorded 5-node walk; block-cooperative matvec (r11/r13).
__global__ __launch_bounds__(256) void wgru_kernel(
    const int*   __restrict__ paths, const float* __restrict__ XGwP,
    const float* __restrict__ wWhP,  const float* __restrict__ wbh,
    const float* __restrict__ wWo,   const float* __restrict__ wbo,
    float* __restrict__ out)
{
    __shared__ float hw_s[4][HD];
    __shared__ float part_s[4][4][6][64];
    const int wid  = threadIdx.x >> 6;
    const int lane = threadIdx.x & 63;
    const int node = blockIdx.x*4 + wid;

    float h0 = 0.f, h1 = 0.f;
    float wb[6], hg[6];
#pragma unroll
    for (int m=0;m<6;m++){ wb[m] = wbh[lane+64*m]; hg[m] = wb[m]; }
    const int* p = paths + (size_t)node*8;

#pragma unroll
    for (int s=0; s<=TT; s++){
        const int c = p[s];
        const float4* xr = (const float4*)(XGwP + ((size_t)c*64 + lane)*8);
        const float4 A = xr[0], B = xr[1];
        float r = fsig (A.x + hg[0]);
        float z = fsig (A.z + hg[2]);
        float n = ftanh(B.x + r*hg[4]);
        h0 = (1.f-z)*n + z*h0;
        r = fsig (A.y + hg[1]);
        z = fsig (A.w + hg[3]);
        n = ftanh(B.y + r*hg[5]);
        h1 = (1.f-z)*n + z*h1;
        if (s < TT){
            hw_s[wid][lane] = h0;  hw_s[wid][lane+64] = h1;
            __syncthreads();
            float pacc[4][6];
#pragma unroll
            for (int j=0;j<4;j++)
#pragma unroll
                for (int m=0;m<6;m++) pacc[j][m] = 0.f;
            const float4* wr = (const float4*)(wWhP + (size_t)lane*8);
#pragma unroll 4
            for (int kk=0; kk<32; kk++){
                const int k = wid*32 + kk;
                const float4 W0 = wr[k*128], W1 = wr[k*128+1];
#pragma unroll
                for (int j=0;j<4;j++){
                    const float hk = hw_s[j][k];
                    pacc[j][0] += hk*W0.x; pacc[j][1] += hk*W0.y;
                    pacc[j][2] += hk*W0.z; pacc[j][3] += hk*W0.w;
                    pacc[j][4] += hk*W1.x; pacc[j][5] += hk*W1.y;
                }
            }
#pragma unroll
            for (int j=0;j<4;j++)
#pragma unroll
                for (int m=0;m<6;m++) part_s[wid][j][m][lane] = pacc[j][m];
            __syncthreads();
#pragma unroll
            for (int m=0;m<6;m++)
                hg[m] = wb[m] + part_s[0][wid][m][lane] + part_s[1][wid][m][lane]
                              + part_s[2][wid][m][lane] + part_s[3][wid][m][lane];
        }
    }
    hw_s[wid][lane] = h0;  hw_s[wid][lane+64] = h1;
    __syncthreads();

    float acc = wbo[lane];                 // CD == 64 == wave width
    const float* wcol = wWo + lane;
    for (int i=0;i<HD;i++) acc += hw_s[wid][i] * wcol[(size_t)i*CD];
    out[(size_t)node*CD + lane] = acc;
}

extern "C" void kernel_launch(void* const* d_in, const int* in_sizes, int n_in,
                              void* d_out, int out_size, void* d_ws, size_t ws_size,
                              hipStream_t stream)
{
    const float* attr  = (const float*)d_in[0];
    const int*   nbrs  = (const int*)  d_in[1];
    const float* noise = (const float*)d_in[2];
    const float* dWx = (const float*)d_in[3];
    const float* dWh = (const float*)d_in[4];
    const float* dbx = (const float*)d_in[5];
    const float* dbh = (const float*)d_in[6];
    const float* dWo = (const float*)d_in[7];
    const float* dbo = (const float*)d_in[8];
    const float* wWx = (const float*)d_in[9];
    const float* wWh = (const float*)d_in[10];
    const float* wbx = (const float*)d_in[11];
    const float* wbh = (const float*)d_in[12];
    const float* wWo = (const float*)d_in[13];
    const float* wbo = (const float*)d_in[14];
    float* out = (float*)d_out;

    char* ws = (char*)d_ws;
    float* XGfP      = (float*)(ws);                 // 16,384,000 B
    float* XGrP      = (float*)(ws + 16384000);      // 12,288,000 B
    float* XGwP      = (float*)(ws + 28672000);      // 16,384,000 B
    float* dWhP      = (float*)(ws + 45056000);      // 262,144 B
    float* wWhP      = (float*)(ws + 45318144);      // 262,144 B
    int*   paths     = (int*)  (ws + 45580288);      // 256,000 B
    int*   fail_list = (int*)  (ws + 45836288);      // 4 bins x 32,000 B
    int*   fail_cnt  = (int*)  (ws + 45964288);      // 16 B  (total ~46.0 MB)

    hipMemsetAsync(fail_cnt, 0, 4*sizeof(int), stream);

    xg_kernel<<<NN/8, G3, 0, stream>>>(attr, dWx, dbx, XGfP, XGrP);
    xg_kernel<<<NN/8, G3, 0, stream>>>(attr, wWx, wbx, XGwP, nullptr);
    repack_kernel<<<(HD*64*8)/256, 256, 0, stream>>>(dWh, dWhP);
    repack_kernel<<<(HD*64*8)/256, 256, 0, stream>>>(wWh, wWhP);

    walk_kernel<<<NN/4, 256, 0, stream>>>(nbrs, noise, XGfP, dWhP,
                                          dbh, dWo, dbo,
                                          paths, fail_cnt, fail_list, out);
    fix_kernel<<<2000, 256, 0, stream>>>(nbrs, noise, XGfP, XGrP,
                                         dWhP, dbh, dWo, dbo,
                                         fail_cnt, fail_list, paths, out);
    wgru_kernel<<<NN/4, 256, 0, stream>>>(paths, XGwP, wWhP, wbh, wWo, wbo, out);
}

// Round 17
// 492.844 us; speedup vs baseline: 1.1001x; 1.0004x over previous
//
#include <hip/hip_runtime.h>
#include <math.h>

#define NN 8000   // nodes
#define CD 64     // node feature dim / C_OUT
#define DG 16     // neighbors per node
#define HD 128    // GRU hidden
#define G3 384    // 3*HD
#define TT 4      // walk steps
// Worst-case f32 noisy-score error bound ~1e-3; MARGIN = 4e-3 (proven r8-r15).
#define MARGIN 4e-3f

#if __has_builtin(__builtin_amdgcn_rcpf)
#define RCP(x) __builtin_amdgcn_rcpf(x)
#else
#define RCP(x) (1.f/(x))
#endif

// fast f32 (walk + wgru; error ~1e-6 << MARGIN)
__device__ __forceinline__ float fsig (float x){ return RCP(1.f + __expf(-x)); }
__device__ __forceinline__ float ftanh(float x){ return 1.f - 2.f*RCP(1.f + __expf(2.f*x)); }

// fast f64 exp: range-reduced 13-term Horner, ~3 ulp (validated r9-r15).
__device__ __forceinline__ double fexp64(double x){
    const double LOG2E  = 1.4426950408889634074;
    const double LN2_HI = 6.93147180369123816490e-01;
    const double LN2_LO = 1.90821492927058770002e-10;
    x = fmin(fmax(x, -700.0), 700.0);
    double fn = rint(x * LOG2E);
    double r  = fma(-fn, LN2_HI, x);
    r = fma(-fn, LN2_LO, r);
    double p = 1.6059043836821613e-10;            // 1/13!
    p = fma(p, r, 2.0876756987868099e-09);
    p = fma(p, r, 2.5052108385441719e-08);
    p = fma(p, r, 2.7557319223985893e-07);
    p = fma(p, r, 2.7557319223985888e-06);
    p = fma(p, r, 2.4801587301587302e-05);
    p = fma(p, r, 1.9841269841269841e-04);
    p = fma(p, r, 1.3888888888888889e-03);
    p = fma(p, r, 8.3333333333333332e-03);
    p = fma(p, r, 4.1666666666666664e-02);
    p = fma(p, r, 1.6666666666666666e-01);
    p = fma(p, r, 0.5);
    p = fma(p, r, 1.0);
    p = fma(p, r, 1.0);
    long long bits = __double_as_longlong(p) + ((long long)(int)fn << 52);
    return __longlong_as_double(bits);
}
__device__ __forceinline__ double sig64f (double x){ return 1.0/(1.0 + fexp64(-x)); }
__device__ __forceinline__ double tanh64f(double x){ return 1.0 - 2.0/(fexp64(2.0*x) + 1.0); }

// XG precompute in f64; emit packed-hi [n][64][8] (+ optional residual [n][64][6]).
__global__ __launch_bounds__(384) void xg_kernel(const float* __restrict__ A,
    const float* __restrict__ W, const float* __restrict__ b,
    float* __restrict__ hiP, float* __restrict__ loP)
{
    __shared__ float a_s[8][64];
    const int g  = threadIdx.x;        // 0..383
    const int l  = g & 63, q = g >> 6;
    const int n0 = blockIdx.x * 8;
    for (int idx = threadIdx.x; idx < 8*64; idx += 384)
        a_s[idx>>6][idx&63] = A[(size_t)n0*64 + idx];
    __syncthreads();
    double acc[8];
    const double bg = (double)b[g];
#pragma unroll
    for (int j=0;j<8;j++) acc[j] = bg;
    for (int c=0;c<64;c++){
        const double w = (double)W[c*G3 + g];
#pragma unroll
        for (int j=0;j<8;j++) acc[j] += (double)a_s[j][c]*w;
    }
#pragma unroll
    for (int j=0;j<8;j++){
        const size_t base = (size_t)(n0+j)*64 + l;
        const float hi = (float)acc[j];
        hiP[base*8 + q] = hi;
        if (q < 2) hiP[base*8 + 6 + q] = 0.f;       // zero pad slots
        if (loP) loP[base*6 + q] = (float)(acc[j] - (double)hi);
    }
}

// Repack Wh [k][384] -> [k][lane][8] (slot m = W[k][64*m+lane], slots 6,7 = 0).
__global__ __launch_bounds__(256) void repack_kernel(const float* __restrict__ W,
                                                     float* __restrict__ P)
{
    const int idx = blockIdx.x*256 + threadIdx.x;   // 0 .. 128*512-1
    const int k = idx >> 9, rem = idx & 511, l = rem >> 3, s = rem & 7;
    P[idx] = (s < 6) ? W[k*G3 + s*64 + l] : 0.f;
}

// Phase 1: pure-f32 walk (r13 structure). Records the 4-bit trip mask per
// node, binned by LAST tripped step (r16) so fix blocks get uniform replay
// lengths and can early-break.
__global__ __launch_bounds__(256) void walk_kernel(
    const int*   __restrict__ nbrs,  const float* __restrict__ noise,
    const float* __restrict__ XGfP,  const float* __restrict__ dWhP,
    const float* __restrict__ dbh,   const float* __restrict__ dWo,
    const float* __restrict__ dbo,
    int* __restrict__ paths, int* __restrict__ fail_cnt, int* __restrict__ fail_list,
    float* __restrict__ out)
{
    __shared__ float hf_s[4][HD];
    __shared__ float part_s[4][4][6][64];

    const int wid  = threadIdx.x >> 6;
    const int lane = threadIdx.x & 63;
    const int node = blockIdx.x*4 + wid;

    float h0 = 0.f, h1 = 0.f;
    float dbhf[6], hgf[6];
#pragma unroll
    for (int m=0;m<6;m++){ dbhf[m] = dbh[lane+64*m]; hgf[m] = dbhf[m]; }
    const float wo0f0 = dWo[lane*CD];
    const float wo0f1 = dWo[(lane+64)*CD];
    const float dbo0f = dbo[0];

    int cur = node;
    int ch0=0, ch1=0, ch2=0, ch3=0;
    int tripmask = 0;

    for (int t=0;t<TT;t++){
        if      (t==0) ch0 = cur;
        else if (t==1) ch1 = cur;
        else if (t==2) ch2 = cur;
        else           ch3 = cur;

        // ---- extend prefix (packed row: 2 x b128) ----
        {
            const float4* xr = (const float4*)(XGfP + ((size_t)cur*64 + lane)*8);
            const float4 A = xr[0], B = xr[1];
            float r = fsig (A.x + hgf[0]);
            float z = fsig (A.z + hgf[2]);
            float n = ftanh(B.x + r*hgf[4]);
            h0 = (1.f-z)*n + z*h0;
            r = fsig (A.y + hgf[1]);
            z = fsig (A.w + hgf[3]);
            n = ftanh(B.y + r*hgf[5]);
            h1 = (1.f-z)*n + z*h1;
        }
        hf_s[wid][lane] = h0;  hf_s[wid][lane+64] = h1;
        __syncthreads();

        // ---- cooperative matvec: wave wid covers k = 32*wid .. 32*wid+31 ----
        {
            float pacc[4][6];
#pragma unroll
            for (int j=0;j<4;j++)
#pragma unroll
                for (int m=0;m<6;m++) pacc[j][m] = 0.f;
            const float4* wr = (const float4*)(dWhP + (size_t)lane*8);
#pragma unroll 4
            for (int kk=0; kk<32; kk++){
                const int k = wid*32 + kk;
                const float4 W0 = wr[k*128], W1 = wr[k*128+1];
#pragma unroll
                for (int j=0;j<4;j++){
                    const float hk = hf_s[j][k];
                    pacc[j][0] += hk*W0.x; pacc[j][1] += hk*W0.y;
                    pacc[j][2] += hk*W0.z; pacc[j][3] += hk*W0.w;
                    pacc[j][4] += hk*W1.x; pacc[j][5] += hk*W1.y;
                }
            }
#pragma unroll
            for (int j=0;j<4;j++)
#pragma unroll
                for (int m=0;m<6;m++) part_s[wid][j][m][lane] = pacc[j][m];
        }
        __syncthreads();

#pragma unroll
        for (int m=0;m<6;m++)
            hgf[m] = dbhf[m] + part_s[0][wid][m][lane] + part_s[1][wid][m][lane]
                             + part_s[2][wid][m][lane] + part_s[3][wid][m][lane];

        // ---- 16 candidates, per-wave ----
        int   nbrv = (lane < DG) ? nbrs[(size_t)cur*DG + lane] : 0;
        float nz   = (lane < DG) ? noise[((size_t)t*NN + node)*DG + lane] : 0.f;
        float lf = -3.0e38f;
#pragma unroll
        for (int g=0; g<4; g++){
            float4 CA[4], CB[4];
#pragma unroll
            for (int j=0;j<4;j++){
                const int nd = __shfl(nbrv, g*4+j);
                const float4* cr = (const float4*)(XGfP + ((size_t)nd*64 + lane)*8);
                CA[j] = cr[0];  CB[j] = cr[1];
            }
            float part[4];
#pragma unroll
            for (int j=0;j<4;j++){
                float r = fsig (CA[j].x + hgf[0]);
                float z = fsig (CA[j].z + hgf[2]);
                float n = ftanh(CB[j].x + r*hgf[4]);
                part[j]  = ((1.f-z)*n + z*h0) * wo0f0;
                r = fsig (CA[j].y + hgf[1]);
                z = fsig (CA[j].w + hgf[3]);
                n = ftanh(CB[j].y + r*hgf[5]);
                part[j] += ((1.f-z)*n + z*h1) * wo0f1;
            }
#pragma unroll
            for (int off=32; off>0; off>>=1){
#pragma unroll
                for (int j=0;j<4;j++) part[j] += __shfl_xor(part[j], off);
            }
#pragma unroll
            for (int j=0;j<4;j++) if (lane == g*4+j) lf = part[j] + dbo0f;
        }

        // ---- softmax + noisy argmax + top-2 margin ----
        float v  = (lane < DG) ? lf : -3.0e38f;
        float mx = v;
#pragma unroll
        for (int off=32; off>0; off>>=1) mx = fmaxf(mx, __shfl_xor(mx, off));
        float e = (lane < DG) ? __expf(v - mx) : 0.f;
        float s = e;
#pragma unroll
        for (int off=32; off>0; off>>=1) s += __shfl_xor(s, off);
        const float normf = mx + __logf(s);

        float noisyf = (lane < DG) ? __expf(v - normf) + 0.01f*nz : -3.0e38f;
        int   idx = lane;
        float bv  = noisyf;
#pragma unroll
        for (int off=32; off>0; off>>=1){
            float ov = __shfl_xor(bv, off);
            int   oi = __shfl_xor(idx, off);
            if (ov > bv || (ov == bv && oi < idx)){ bv = ov; idx = oi; }
        }
        float sv = (lane == idx || lane >= DG) ? -3.0e38f : noisyf;
#pragma unroll
        for (int off=32; off>0; off>>=1) sv = fmaxf(sv, __shfl_xor(sv, off));

        if ((bv - sv) < MARGIN) tripmask |= (1 << t);   // wave-uniform

        const float lpf = __shfl(v, idx) - normf;
        if (lane == 0) out[NN*CD + node*TT + t] = lpf;
        cur = __shfl(nbrv, idx);
    }

    if (lane == 0){
        int* p = paths + (size_t)node*8;
        p[0]=ch0; p[1]=ch1; p[2]=ch2; p[3]=ch3; p[4]=cur;
        if (tripmask){
            const int bin = 31 - __clz(tripmask);   // last tripped step 0..3
            const int slot = atomicAdd(&fail_cnt[bin], 1);
            fail_list[bin*NN + slot] = node | (tripmask << 16);
        }
    }
}

// Phase 2: exact-f64 redo (r15 structure + r16 early termination):
//  - entries binned by last-tripped-step -> block's 4 waves share replay len.
//  - per-wave done flag (no remaining mask bits, not diverged): skips extend
//    gathers + fexp64 (stale h_s feeds only its own never-read partials).
//  - block-uniform break via __syncthreads_and once all 4 waves are done.
// All computed f64 values are bit-identical to r15 — only dead work elided.
__global__ __launch_bounds__(256) void fix_kernel(
    const int*   __restrict__ nbrs,  const float* __restrict__ noise,
    const float* __restrict__ XGfP,  const float* __restrict__ XGrP,
    const float* __restrict__ dWhP,  const float* __restrict__ dbh,
    const float* __restrict__ dWo,   const float* __restrict__ dbo,
    const int* __restrict__ fail_cnt, const int* __restrict__ fail_list,
    int* __restrict__ paths, float* __restrict__ out)
{
    __shared__ double smem[3584];            // 28672 B: h_s[512] + dbuf[3072]
    double* h_s  = smem;                     // [4][HD]
    double* dbuf = smem + 512;               // [2][4][6][64]

    const int wid  = threadIdx.x >> 6;
    const int lane = threadIdx.x & 63;
    const int n0c = fail_cnt[0], n1c = fail_cnt[1], n2c = fail_cnt[2], n3c = fail_cnt[3];
    const int total = n0c + n1c + n2c + n3c;
    if (blockIdx.x*4 >= total) return;       // whole-block early exit (uniform)

    const int  ii     = blockIdx.x*4 + wid;
    const bool active = (ii < total);
    int entry = 0;
    if (active){
        int b, loc;
        if      (ii < n0c)            { b=0; loc=ii; }
        else if (ii < n0c+n1c)        { b=1; loc=ii-n0c; }
        else if (ii < n0c+n1c+n2c)    { b=2; loc=ii-n0c-n1c; }
        else                          { b=3; loc=ii-n0c-n1c-n2c; }
        entry = fail_list[b*NN + loc];
    }
    const int  node = entry & 0xFFFF;
    const int  mask = active ? (entry >> 16) : 0;   // idle: done immediately
    const int* pw   = paths + (size_t)node*8;

    double db64[6];
#pragma unroll
    for (int m=0;m<6;m++) db64[m] = (double)dbh[lane+64*m];
    const double wo0d0 = (double)dWo[lane*CD];
    const double wo0d1 = (double)dWo[(lane+64)*CD];
    const double dbo0d = (double)dbo[0];

    double H0 = 0.0, H1 = 0.0;
    double g64[6];
#pragma unroll
    for (int m=0;m<6;m++) g64[m] = db64[m];
    int  cur = node;
    int  c0=0,c1=0,c2=0,c3=0;
    bool diverged = false;

    for (int t=0;t<TT;t++){
        // done: no remaining mask bits and still on the certified path
        const bool done = !diverged && ((mask >> t) == 0);
        if (__syncthreads_and(done ? 1 : 0)) break;   // block-uniform

        if      (t==0) c0 = cur;
        else if (t==1) c1 = cur;
        else if (t==2) c2 = cur;
        else           c3 = cur;

        // ---- extend (f64 = hi + residual); skipped for done waves ----
        if (!done){
            const size_t b = (size_t)cur*64 + lane;
            const float* hi = XGfP + b*8;
            const float* lo = XGrP + b*6;
            double r = sig64f (((double)hi[0]+(double)lo[0]) + g64[0]);
            double z = sig64f (((double)hi[2]+(double)lo[2]) + g64[2]);
            double n = tanh64f(((double)hi[4]+(double)lo[4]) + r*g64[4]);
            H0 = (1.0-z)*n + z*H0;
            r = sig64f (((double)hi[1]+(double)lo[1]) + g64[1]);
            z = sig64f (((double)hi[3]+(double)lo[3]) + g64[3]);
            n = tanh64f(((double)hi[5]+(double)lo[5]) + r*g64[5]);
            H1 = (1.0-z)*n + z*H1;
            h_s[wid*HD + lane] = H0;  h_s[wid*HD + lane + 64] = H1;
        }
        __syncthreads();                            // (1) h ready

        // ---- cooperative f64 matvec, 3-stage pairwise reduction (28KB) ----
        double pacc[4][6];
#pragma unroll
        for (int j=0;j<4;j++)
#pragma unroll
            for (int m=0;m<6;m++) pacc[j][m] = 0.0;
        {
            const float4* wv = (const float4*)(dWhP + (size_t)lane*8);
#pragma unroll 4
            for (int kk=0; kk<32; kk++){
                const int k = wid*32 + kk;
                const float4 W0 = wv[k*128], W1 = wv[k*128+1];
#pragma unroll
                for (int j=0;j<4;j++){
                    const double hk = h_s[j*HD + k];
                    pacc[j][0] += hk*(double)W0.x; pacc[j][1] += hk*(double)W0.y;
                    pacc[j][2] += hk*(double)W0.z; pacc[j][3] += hk*(double)W0.w;
                    pacc[j][4] += hk*(double)W1.x; pacc[j][5] += hk*(double)W1.y;
                }
            }
        }
        if (wid >= 2){
#pragma unroll
            for (int j=0;j<4;j++)
#pragma unroll
                for (int m=0;m<6;m++)
                    dbuf[(((wid-2)*4+j)*6+m)*64 + lane] = pacc[j][m];
        }
        __syncthreads();                            // (2) writers 2,3 published
        if (wid < 2){
#pragma unroll
            for (int j=0;j<4;j++)
#pragma unroll
                for (int m=0;m<6;m++){
                    pacc[j][m] += dbuf[((wid*4+j)*6+m)*64 + lane];
                    dbuf[((wid*4+j)*6+m)*64 + lane] = pacc[j][m];
                }
        }
        __syncthreads();                            // (3) pair sums published
        if (!done){
#pragma unroll
            for (int m=0;m<6;m++)
                g64[m] = db64[m] + dbuf[((0*4+wid)*6+m)*64 + lane]
                                 + dbuf[((1*4+wid)*6+m)*64 + lane];
        }

        // ---- certified step (not tripped, on recorded path): skip scoring ----
        if (!diverged && !((mask >> t) & 1)){
            cur = pw[t+1];
            continue;                               // no barriers below — safe
        }

        // ---- 16 candidates f64, 4 groups of 4 with prefetch ----
        int   nbrv = (lane < DG) ? nbrs[(size_t)cur*DG + lane] : 0;
        float nz   = (lane < DG) ? noise[((size_t)t*NN + node)*DG + lane] : 0.f;
        double lv = -1e300;
#pragma unroll
        for (int g=0; g<4; g++){
            float ch[4][6], cl[4][6];
#pragma unroll
            for (int j=0;j<4;j++){
                const int nd = __shfl(nbrv, g*4+j);
                const size_t b = (size_t)nd*64 + lane;
                const float* hi = XGfP + b*8;
                const float* lo = XGrP + b*6;
#pragma unroll
                for (int q=0;q<6;q++){ ch[j][q]=hi[q]; cl[j][q]=lo[q]; }
            }
#pragma unroll
            for (int j=0;j<4;j++){
                double r = sig64f (((double)ch[j][0]+(double)cl[j][0]) + g64[0]);
                double z = sig64f (((double)ch[j][2]+(double)cl[j][2]) + g64[2]);
                double n = tanh64f(((double)ch[j][4]+(double)cl[j][4]) + r*g64[4]);
                double part = ((1.0-z)*n + z*H0) * wo0d0;
                r = sig64f (((double)ch[j][1]+(double)cl[j][1]) + g64[1]);
                z = sig64f (((double)ch[j][3]+(double)cl[j][3]) + g64[3]);
                n = tanh64f(((double)ch[j][5]+(double)cl[j][5]) + r*g64[5]);
                part += ((1.0-z)*n + z*H1) * wo0d1;
#pragma unroll
                for (int off=32; off>0; off>>=1) part += __shfl_xor(part, off);
                if (lane == g*4+j) lv = part + dbo0d;
            }
        }

        // ---- softmax + noisy argmax (identical numerics to r9-r15) ----
        double dv = (lane < DG) ? lv : -1e300;
        double dmx = dv;
#pragma unroll
        for (int off=32; off>0; off>>=1) dmx = fmax(dmx, __shfl_xor(dmx, off));
        double de = (lane < DG) ? fexp64(dv - dmx) : 0.0;
        double ds = de;
#pragma unroll
        for (int off=32; off>0; off>>=1) ds += __shfl_xor(ds, off);
        const double dnorm = dmx + log(ds);
        double dnoisy = (lane < DG) ? fexp64(dv - dnorm) + 0.01*(double)nz : -1e300;
        int di = lane;
#pragma unroll
        for (int off=32; off>0; off>>=1){
            double ov = __shfl_xor(dnoisy, off);
            int    oi = __shfl_xor(di, off);
            if (ov > dnoisy || (ov == dnoisy && oi < di)){ dnoisy = ov; di = oi; }
        }
        const double lpfix = __shfl(dv, di) - dnorm;
        if (active && lane == 0) out[NN*CD + node*TT + t] = (float)lpfix;
        const int newcur = __shfl(nbrv, di);
        diverged = diverged || (newcur != pw[t+1]);
        cur = newcur;
    }

    // Path rewrite only needed when the trajectory actually changed; a
    // non-diverged node's recorded path is already exact.
    if (active && diverged && lane == 0){
        int* p = paths + (size_t)node*8;
        p[0]=c0; p[1]=c1; p[2]=c2; p[3]=c3; p[4]=cur;
    }
}

// w-GRU over the recorded 5-node walk; block-cooperative matvec (r11/r13).
__global__ __launch_bounds__(256) void wgru_kernel(
    const int*   __restrict__ paths, const float* __restrict__ XGwP,
    const float* __restrict__ wWhP,  const float* __restrict__ wbh,
    const float* __restrict__ wWo,   const float* __restrict__ wbo,
    float* __restrict__ out)
{
    __shared__ float hw_s[4][HD];
    __shared__ float part_s[4][4][6][64];
    const int wid  = threadIdx.x >> 6;
    const int lane = threadIdx.x & 63;
    const int node = blockIdx.x*4 + wid;

    float h0 = 0.f, h1 = 0.f;
    float wb[6], hg[6];
#pragma unroll
    for (int m=0;m<6;m++){ wb[m] = wbh[lane+64*m]; hg[m] = wb[m]; }
    const int* p = paths + (size_t)node*8;

#pragma unroll
    for (int s=0; s<=TT; s++){
        const int c = p[s];
        const float4* xr = (const float4*)(XGwP + ((size_t)c*64 + lane)*8);
        const float4 A = xr[0], B = xr[1];
        float r = fsig (A.x + hg[0]);
        float z = fsig (A.z + hg[2]);
        float n = ftanh(B.x + r*hg[4]);
        h0 = (1.f-z)*n + z*h0;
        r = fsig (A.y + hg[1]);
        z = fsig (A.w + hg[3]);
        n = ftanh(B.y + r*hg[5]);
        h1 = (1.f-z)*n + z*h1;
        if (s < TT){
            hw_s[wid][lane] = h0;  hw_s[wid][lane+64] = h1;
            __syncthreads();
            float pacc[4][6];
#pragma unroll
            for (int j=0;j<4;j++)
#pragma unroll
                for (int m=0;m<6;m++) pacc[j][m] = 0.f;
            const float4* wr = (const float4*)(wWhP + (size_t)lane*8);
#pragma unroll 4
            for (int kk=0; kk<32; kk++){
                const int k = wid*32 + kk;
                const float4 W0 = wr[k*128], W1 = wr[k*128+1];
#pragma unroll
                for (int j=0;j<4;j++){
                    const float hk = hw_s[j][k];
                    pacc[j][0] += hk*W0.x; pacc[j][1] += hk*W0.y;
                    pacc[j][2] += hk*W0.z; pacc[j][3] += hk*W0.w;
                    pacc[j][4] += hk*W1.x; pacc[j][5] += hk*W1.y;
                }
            }
#pragma unroll
            for (int j=0;j<4;j++)
#pragma unroll
                for (int m=0;m<6;m++) part_s[wid][j][m][lane] = pacc[j][m];
            __syncthreads();
#pragma unroll
            for (int m=0;m<6;m++)
                hg[m] = wb[m] + part_s[0][wid][m][lane] + part_s[1][wid][m][lane]
                              + part_s[2][wid][m][lane] + part_s[3][wid][m][lane];
        }
    }
    hw_s[wid][lane] = h0;  hw_s[wid][lane+64] = h1;
    __syncthreads();

    float acc = wbo[lane];                 // CD == 64 == wave width
    const float* wcol = wWo + lane;
    for (int i=0;i<HD;i++) acc += hw_s[wid][i] * wcol[(size_t)i*CD];
    out[(size_t)node*CD + lane] = acc;
}

extern "C" void kernel_launch(void* const* d_in, const int* in_sizes, int n_in,
                              void* d_out, int out_size, void* d_ws, size_t ws_size,
                              hipStream_t stream)
{
    const float* attr  = (const float*)d_in[0];
    const int*   nbrs  = (const int*)  d_in[1];
    const float* noise = (const float*)d_in[2];
    const float* dWx = (const float*)d_in[3];
    const float* dWh = (const float*)d_in[4];
    const float* dbx = (const float*)d_in[5];
    const float* dbh = (const float*)d_in[6];
    const float* dWo = (const float*)d_in[7];
    const float* dbo = (const float*)d_in[8];
    const float* wWx = (const float*)d_in[9];
    const float* wWh = (const float*)d_in[10];
    const float* wbx = (const float*)d_in[11];
    const float* wbh = (const float*)d_in[12];
    const float* wWo = (const float*)d_in[13];
    const float* wbo = (const float*)d_in[14];
    float* out = (float*)d_out;

    char* ws = (char*)d_ws;
    float* XGfP      = (float*)(ws);                 // 16,384,000 B
    float* XGrP      = (float*)(ws + 16384000);      // 12,288,000 B
    float* XGwP      = (float*)(ws + 28672000);      // 16,384,000 B
    float* dWhP      = (float*)(ws + 45056000);      // 262,144 B
    float* wWhP      = (float*)(ws + 45318144);      // 262,144 B
    int*   paths     = (int*)  (ws + 45580288);      // 256,000 B
    int*   fail_list = (int*)  (ws + 45836288);      // 4 bins x 32,000 B
    int*   fail_cnt  = (int*)  (ws + 45964288);      // 16 B  (total ~46.0 MB)

    hipMemsetAsync(fail_cnt, 0, 4*sizeof(int), stream);

    xg_kernel<<<NN/8, G3, 0, stream>>>(attr, dWx, dbx, XGfP, XGrP);
    xg_kernel<<<NN/8, G3, 0, stream>>>(attr, wWx, wbx, XGwP, nullptr);
    repack_kernel<<<(HD*64*8)/256, 256, 0, stream>>>(dWh, dWhP);
    repack_kernel<<<(HD*64*8)/256, 256, 0, stream>>>(wWh, wWhP);

    walk_kernel<<<NN/4, 256, 0, stream>>>(nbrs, noise, XGfP, dWhP,
                                          dbh, dWo, dbo,
                                          paths, fail_cnt, fail_list, out);
    fix_kernel<<<2000, 256, 0, stream>>>(nbrs, noise, XGfP, XGrP,
                                         dWhP, dbh, dWo, dbo,
                                         fail_cnt, fail_list, paths, out);
    wgru_kernel<<<NN/4, 256, 0, stream>>>(paths, XGwP, wWhP, wbh, wWo, wbo, out);
}

// Round 18
// 486.645 us; speedup vs baseline: 1.1141x; 1.0127x over previous
//
#include <hip/hip_runtime.h>
#include <math.h>

#define NN 8000   // nodes
#define CD 64     // node feature dim / C_OUT
#define DG 16     // neighbors per node
#define HD 128    // GRU hidden
#define G3 384    // 3*HD
#define TT 4      // walk steps
// Worst-case f32 noisy-score error bound ~1e-3; MARGIN = 4e-3 (proven r8-r17).
#define MARGIN 4e-3f

#if __has_builtin(__builtin_amdgcn_rcpf)
#define RCP(x) __builtin_amdgcn_rcpf(x)
#else
#define RCP(x) (1.f/(x))
#endif

// fast f32 (walk + wgru; error ~1e-6 << MARGIN)
__device__ __forceinline__ float fsig (float x){ return RCP(1.f + __expf(-x)); }
__device__ __forceinline__ float ftanh(float x){ return 1.f - 2.f*RCP(1.f + __expf(2.f*x)); }

// fast f64 exp: range-reduced 13-term Horner, ~3 ulp (validated r9-r17).
__device__ __forceinline__ double fexp64(double x){
    const double LOG2E  = 1.4426950408889634074;
    const double LN2_HI = 6.93147180369123816490e-01;
    const double LN2_LO = 1.90821492927058770002e-10;
    x = fmin(fmax(x, -700.0), 700.0);
    double fn = rint(x * LOG2E);
    double r  = fma(-fn, LN2_HI, x);
    r = fma(-fn, LN2_LO, r);
    double p = 1.6059043836821613e-10;            // 1/13!
    p = fma(p, r, 2.0876756987868099e-09);
    p = fma(p, r, 2.5052108385441719e-08);
    p = fma(p, r, 2.7557319223985893e-07);
    p = fma(p, r, 2.7557319223985888e-06);
    p = fma(p, r, 2.4801587301587302e-05);
    p = fma(p, r, 1.9841269841269841e-04);
    p = fma(p, r, 1.3888888888888889e-03);
    p = fma(p, r, 8.3333333333333332e-03);
    p = fma(p, r, 4.1666666666666664e-02);
    p = fma(p, r, 1.6666666666666666e-01);
    p = fma(p, r, 0.5);
    p = fma(p, r, 1.0);
    p = fma(p, r, 1.0);
    long long bits = __double_as_longlong(p) + ((long long)(int)fn << 52);
    return __longlong_as_double(bits);
}
__device__ __forceinline__ double sig64f (double x){ return 1.0/(1.0 + fexp64(-x)); }
__device__ __forceinline__ double tanh64f(double x){ return 1.0 - 2.0/(fexp64(2.0*x) + 1.0); }

// XG precompute in f64; emit packed-hi [n][64][8] (+ optional residual [n][64][6]).
__global__ __launch_bounds__(384) void xg_kernel(const float* __restrict__ A,
    const float* __restrict__ W, const float* __restrict__ b,
    float* __restrict__ hiP, float* __restrict__ loP)
{
    __shared__ float a_s[8][64];
    const int g  = threadIdx.x;        // 0..383
    const int l  = g & 63, q = g >> 6;
    const int n0 = blockIdx.x * 8;
    for (int idx = threadIdx.x; idx < 8*64; idx += 384)
        a_s[idx>>6][idx&63] = A[(size_t)n0*64 + idx];
    __syncthreads();
    double acc[8];
    const double bg = (double)b[g];
#pragma unroll
    for (int j=0;j<8;j++) acc[j] = bg;
    for (int c=0;c<64;c++){
        const double w = (double)W[c*G3 + g];
#pragma unroll
        for (int j=0;j<8;j++) acc[j] += (double)a_s[j][c]*w;
    }
#pragma unroll
    for (int j=0;j<8;j++){
        const size_t base = (size_t)(n0+j)*64 + l;
        const float hi = (float)acc[j];
        hiP[base*8 + q] = hi;
        if (q < 2) hiP[base*8 + 6 + q] = 0.f;       // zero pad slots
        if (loP) loP[base*6 + q] = (float)(acc[j] - (double)hi);
    }
}

// Repack Wh [k][384] -> [k][lane][8] (slot m = W[k][64*m+lane], slots 6,7 = 0).
__global__ __launch_bounds__(256) void repack_kernel(const float* __restrict__ W,
                                                     float* __restrict__ P)
{
    const int idx = blockIdx.x*256 + threadIdx.x;   // 0 .. 128*512-1
    const int k = idx >> 9, rem = idx & 511, l = rem >> 3, s = rem & 7;
    P[idx] = (s < 6) ? W[k*G3 + s*64 + l] : 0.f;
}

// Phase 1: pure-f32 walk, software-pipelined (r18):
//  - next-step XG row / nbrs row / noise issued right after cur is selected
//  - candidate group 0 prefetched BEFORE the matvec (hides under it)
//  - groups 1-3 double-buffered (load-ahead while previous group computes)
//  - 3-stage LDS reduction (12KB) for the cooperative matvec
// Trip mask binned by last-tripped step (r16) for the fix kernel.
__global__ __launch_bounds__(256) void walk_kernel(
    const int*   __restrict__ nbrs,  const float* __restrict__ noise,
    const float* __restrict__ XGfP,  const float* __restrict__ dWhP,
    const float* __restrict__ dbh,   const float* __restrict__ dWo,
    const float* __restrict__ dbo,
    int* __restrict__ paths, int* __restrict__ fail_cnt, int* __restrict__ fail_list,
    float* __restrict__ out)
{
    __shared__ float hf_s[4][HD];            // 2 KB
    __shared__ float dbuf_s[2][4][6][64];    // 12 KB

    const int wid  = threadIdx.x >> 6;
    const int lane = threadIdx.x & 63;
    const int node = blockIdx.x*4 + wid;

    float h0 = 0.f, h1 = 0.f;
    float dbhf[6], hgf[6];
#pragma unroll
    for (int m=0;m<6;m++){ dbhf[m] = dbh[lane+64*m]; hgf[m] = dbhf[m]; }
    const float wo0f0 = dWo[lane*CD];
    const float wo0f1 = dWo[(lane+64)*CD];
    const float dbo0f = dbo[0];

    int cur = node;
    int ch0=0, ch1=0, ch2=0, ch3=0;
    int tripmask = 0;

    // ---- pipeline preload for t=0 ----
    float4 XA, XB; int nbrv; float nz;
    {
        const float4* xr = (const float4*)(XGfP + ((size_t)cur*64 + lane)*8);
        XA = xr[0];  XB = xr[1];
        nbrv = (lane < DG) ? nbrs[(size_t)cur*DG + lane] : 0;
        nz   = (lane < DG) ? noise[(size_t)node*DG + lane] : 0.f;
    }

    float4 PA[4], PB[4], QA[4], QB[4];
    float lf;

    auto loadGroup = [&](float4* A, float4* B, int gbase){
#pragma unroll
        for (int j=0;j<4;j++){
            const int nd = __shfl(nbrv, gbase+j);
            const float4* cr = (const float4*)(XGfP + ((size_t)nd*64 + lane)*8);
            A[j] = cr[0];  B[j] = cr[1];
        }
    };
    auto scoreGroup = [&](const float4* A, const float4* B, int gbase){
        float part[4];
#pragma unroll
        for (int j=0;j<4;j++){
            float r = fsig (A[j].x + hgf[0]);
            float z = fsig (A[j].z + hgf[2]);
            float n = ftanh(B[j].x + r*hgf[4]);
            part[j]  = ((1.f-z)*n + z*h0) * wo0f0;
            r = fsig (A[j].y + hgf[1]);
            z = fsig (A[j].w + hgf[3]);
            n = ftanh(B[j].y + r*hgf[5]);
            part[j] += ((1.f-z)*n + z*h1) * wo0f1;
        }
#pragma unroll
        for (int off=32; off>0; off>>=1){
#pragma unroll
            for (int j=0;j<4;j++) part[j] += __shfl_xor(part[j], off);
        }
#pragma unroll
        for (int j=0;j<4;j++) if (lane == gbase+j) lf = part[j] + dbo0f;
    };

    for (int t=0;t<TT;t++){
        if      (t==0) ch0 = cur;
        else if (t==1) ch1 = cur;
        else if (t==2) ch2 = cur;
        else           ch3 = cur;

        // ---- extend prefix (prefetched row) ----
        {
            float r = fsig (XA.x + hgf[0]);
            float z = fsig (XA.z + hgf[2]);
            float n = ftanh(XB.x + r*hgf[4]);
            h0 = (1.f-z)*n + z*h0;
            r = fsig (XA.y + hgf[1]);
            z = fsig (XA.w + hgf[3]);
            n = ftanh(XB.y + r*hgf[5]);
            h1 = (1.f-z)*n + z*h1;
        }
        hf_s[wid][lane] = h0;  hf_s[wid][lane+64] = h1;
        __syncthreads();                 // (1) all 4 nodes' h visible

        // ---- prefetch candidate group 0 (hides under the matvec) ----
        loadGroup(PA, PB, 0);

        // ---- cooperative matvec, 3-stage pairwise reduction ----
        float pacc[4][6];
#pragma unroll
        for (int j=0;j<4;j++)
#pragma unroll
            for (int m=0;m<6;m++) pacc[j][m] = 0.f;
        {
            const float4* wr = (const float4*)(dWhP + (size_t)lane*8);
#pragma unroll 4
            for (int kk=0; kk<32; kk++){
                const int k = wid*32 + kk;
                const float4 W0 = wr[k*128], W1 = wr[k*128+1];
#pragma unroll
                for (int j=0;j<4;j++){
                    const float hk = hf_s[j][k];
                    pacc[j][0] += hk*W0.x; pacc[j][1] += hk*W0.y;
                    pacc[j][2] += hk*W0.z; pacc[j][3] += hk*W0.w;
                    pacc[j][4] += hk*W1.x; pacc[j][5] += hk*W1.y;
                }
            }
        }
        if (wid >= 2){
#pragma unroll
            for (int j=0;j<4;j++)
#pragma unroll
                for (int m=0;m<6;m++) dbuf_s[wid-2][j][m][lane] = pacc[j][m];
        }
        __syncthreads();                 // (2) writers 2,3 published
        if (wid < 2){
#pragma unroll
            for (int j=0;j<4;j++)
#pragma unroll
                for (int m=0;m<6;m++){
                    pacc[j][m] += dbuf_s[wid][j][m][lane];
                    dbuf_s[wid][j][m][lane] = pacc[j][m];
                }
        }
        __syncthreads();                 // (3) pair sums published
#pragma unroll
        for (int m=0;m<6;m++)
            hgf[m] = dbhf[m] + dbuf_s[0][wid][m][lane] + dbuf_s[1][wid][m][lane];

        // ---- 16 candidates: double-buffered groups of 4 ----
        lf = -3.0e38f;
        loadGroup(QA, QB, 4);   scoreGroup(PA, PB, 0);
        loadGroup(PA, PB, 8);   scoreGroup(QA, QB, 4);
        loadGroup(QA, QB, 12);  scoreGroup(PA, PB, 8);
        scoreGroup(QA, QB, 12);

        // ---- softmax + noisy argmax + top-2 margin ----
        float v  = (lane < DG) ? lf : -3.0e38f;
        float mx = v;
#pragma unroll
        for (int off=32; off>0; off>>=1) mx = fmaxf(mx, __shfl_xor(mx, off));
        float e = (lane < DG) ? __expf(v - mx) : 0.f;
        float s = e;
#pragma unroll
        for (int off=32; off>0; off>>=1) s += __shfl_xor(s, off);
        const float normf = mx + __logf(s);

        float noisyf = (lane < DG) ? __expf(v - normf) + 0.01f*nz : -3.0e38f;
        int   idx = lane;
        float bv  = noisyf;
#pragma unroll
        for (int off=32; off>0; off>>=1){
            float ov = __shfl_xor(bv, off);
            int   oi = __shfl_xor(idx, off);
            if (ov > bv || (ov == bv && oi < idx)){ bv = ov; idx = oi; }
        }
        float sv = (lane == idx || lane >= DG) ? -3.0e38f : noisyf;
#pragma unroll
        for (int off=32; off>0; off>>=1) sv = fmaxf(sv, __shfl_xor(sv, off));

        if ((bv - sv) < MARGIN) tripmask |= (1 << t);   // wave-uniform

        const float lpf = __shfl(v, idx) - normf;
        if (lane == 0) out[NN*CD + node*TT + t] = lpf;
        cur = __shfl(nbrv, idx);

        // ---- prefetch next step's row / neighbors / noise ----
        if (t < TT-1){
            const float4* xr = (const float4*)(XGfP + ((size_t)cur*64 + lane)*8);
            XA = xr[0];  XB = xr[1];
            nbrv = (lane < DG) ? nbrs[(size_t)cur*DG + lane] : 0;
            nz   = (lane < DG) ? noise[((size_t)(t+1)*NN + node)*DG + lane] : 0.f;
        }
    }

    if (lane == 0){
        int* p = paths + (size_t)node*8;
        p[0]=ch0; p[1]=ch1; p[2]=ch2; p[3]=ch3; p[4]=cur;
        if (tripmask){
            const int bin = 31 - __clz(tripmask);   // last tripped step 0..3
            const int slot = atomicAdd(&fail_cnt[bin], 1);
            fail_list[bin*NN + slot] = node | (tripmask << 16);
        }
    }
}

// Phase 2: exact-f64 redo — UNCHANGED from r17 (binned early-break, 28KB LDS,
// mask-selective scoring; all computed f64 values bit-identical to r15-r17).
__global__ __launch_bounds__(256) void fix_kernel(
    const int*   __restrict__ nbrs,  const float* __restrict__ noise,
    const float* __restrict__ XGfP,  const float* __restrict__ XGrP,
    const float* __restrict__ dWhP,  const float* __restrict__ dbh,
    const float* __restrict__ dWo,   const float* __restrict__ dbo,
    const int* __restrict__ fail_cnt, const int* __restrict__ fail_list,
    int* __restrict__ paths, float* __restrict__ out)
{
    __shared__ double smem[3584];            // 28672 B: h_s[512] + dbuf[3072]
    double* h_s  = smem;                     // [4][HD]
    double* dbuf = smem + 512;               // [2][4][6][64]

    const int wid  = threadIdx.x >> 6;
    const int lane = threadIdx.x & 63;
    const int n0c = fail_cnt[0], n1c = fail_cnt[1], n2c = fail_cnt[2], n3c = fail_cnt[3];
    const int total = n0c + n1c + n2c + n3c;
    if (blockIdx.x*4 >= total) return;       // whole-block early exit (uniform)

    const int  ii     = blockIdx.x*4 + wid;
    const bool active = (ii < total);
    int entry = 0;
    if (active){
        int b, loc;
        if      (ii < n0c)            { b=0; loc=ii; }
        else if (ii < n0c+n1c)        { b=1; loc=ii-n0c; }
        else if (ii < n0c+n1c+n2c)    { b=2; loc=ii-n0c-n1c; }
        else                          { b=3; loc=ii-n0c-n1c-n2c; }
        entry = fail_list[b*NN + loc];
    }
    const int  node = entry & 0xFFFF;
    const int  mask = active ? (entry >> 16) : 0;   // idle: done immediately
    const int* pw   = paths + (size_t)node*8;

    double db64[6];
#pragma unroll
    for (int m=0;m<6;m++) db64[m] = (double)dbh[lane+64*m];
    const double wo0d0 = (double)dWo[lane*CD];
    const double wo0d1 = (double)dWo[(lane+64)*CD];
    const double dbo0d = (double)dbo[0];

    double H0 = 0.0, H1 = 0.0;
    double g64[6];
#pragma unroll
    for (int m=0;m<6;m++) g64[m] = db64[m];
    int  cur = node;
    int  c0=0,c1=0,c2=0,c3=0;
    bool diverged = false;

    for (int t=0;t<TT;t++){
        const bool done = !diverged && ((mask >> t) == 0);
        if (__syncthreads_and(done ? 1 : 0)) break;   // block-uniform

        if      (t==0) c0 = cur;
        else if (t==1) c1 = cur;
        else if (t==2) c2 = cur;
        else           c3 = cur;

        // ---- extend (f64 = hi + residual); skipped for done waves ----
        if (!done){
            const size_t b = (size_t)cur*64 + lane;
            const float* hi = XGfP + b*8;
            const float* lo = XGrP + b*6;
            double r = sig64f (((double)hi[0]+(double)lo[0]) + g64[0]);
            double z = sig64f (((double)hi[2]+(double)lo[2]) + g64[2]);
            double n = tanh64f(((double)hi[4]+(double)lo[4]) + r*g64[4]);
            H0 = (1.0-z)*n + z*H0;
            r = sig64f (((double)hi[1]+(double)lo[1]) + g64[1]);
            z = sig64f (((double)hi[3]+(double)lo[3]) + g64[3]);
            n = tanh64f(((double)hi[5]+(double)lo[5]) + r*g64[5]);
            H1 = (1.0-z)*n + z*H1;
            h_s[wid*HD + lane] = H0;  h_s[wid*HD + lane + 64] = H1;
        }
        __syncthreads();                            // (1) h ready

        // ---- cooperative f64 matvec, 3-stage pairwise reduction (28KB) ----
        double pacc[4][6];
#pragma unroll
        for (int j=0;j<4;j++)
#pragma unroll
            for (int m=0;m<6;m++) pacc[j][m] = 0.0;
        {
            const float4* wv = (const float4*)(dWhP + (size_t)lane*8);
#pragma unroll 4
            for (int kk=0; kk<32; kk++){
                const int k = wid*32 + kk;
                const float4 W0 = wv[k*128], W1 = wv[k*128+1];
#pragma unroll
                for (int j=0;j<4;j++){
                    const double hk = h_s[j*HD + k];
                    pacc[j][0] += hk*(double)W0.x; pacc[j][1] += hk*(double)W0.y;
                    pacc[j][2] += hk*(double)W0.z; pacc[j][3] += hk*(double)W0.w;
                    pacc[j][4] += hk*(double)W1.x; pacc[j][5] += hk*(double)W1.y;
                }
            }
        }
        if (wid >= 2){
#pragma unroll
            for (int j=0;j<4;j++)
#pragma unroll
                for (int m=0;m<6;m++)
                    dbuf[(((wid-2)*4+j)*6+m)*64 + lane] = pacc[j][m];
        }
        __syncthreads();                            // (2) writers 2,3 published
        if (wid < 2){
#pragma unroll
            for (int j=0;j<4;j++)
#pragma unroll
                for (int m=0;m<6;m++){
                    pacc[j][m] += dbuf[((wid*4+j)*6+m)*64 + lane];
                    dbuf[((wid*4+j)*6+m)*64 + lane] = pacc[j][m];
                }
        }
        __syncthreads();                            // (3) pair sums published
        if (!done){
#pragma unroll
            for (int m=0;m<6;m++)
                g64[m] = db64[m] + dbuf[((0*4+wid)*6+m)*64 + lane]
                                 + dbuf[((1*4+wid)*6+m)*64 + lane];
        }

        // ---- certified step (not tripped, on recorded path): skip scoring ----
        if (!diverged && !((mask >> t) & 1)){
            cur = pw[t+1];
            continue;                               // no barriers below — safe
        }

        // ---- 16 candidates f64, 4 groups of 4 with prefetch ----
        int   nbrv = (lane < DG) ? nbrs[(size_t)cur*DG + lane] : 0;
        float nz   = (lane < DG) ? noise[((size_t)t*NN + node)*DG + lane] : 0.f;
        double lv = -1e300;
#pragma unroll
        for (int g=0; g<4; g++){
            float ch[4][6], cl[4][6];
#pragma unroll
            for (int j=0;j<4;j++){
                const int nd = __shfl(nbrv, g*4+j);
                const size_t b = (size_t)nd*64 + lane;
                const float* hi = XGfP + b*8;
                const float* lo = XGrP + b*6;
#pragma unroll
                for (int q=0;q<6;q++){ ch[j][q]=hi[q]; cl[j][q]=lo[q]; }
            }
#pragma unroll
            for (int j=0;j<4;j++){
                double r = sig64f (((double)ch[j][0]+(double)cl[j][0]) + g64[0]);
                double z = sig64f (((double)ch[j][2]+(double)cl[j][2]) + g64[2]);
                double n = tanh64f(((double)ch[j][4]+(double)cl[j][4]) + r*g64[4]);
                double part = ((1.0-z)*n + z*H0) * wo0d0;
                r = sig64f (((double)ch[j][1]+(double)cl[j][1]) + g64[1]);
                z = sig64f (((double)ch[j][3]+(double)cl[j][3]) + g64[3]);
                n = tanh64f(((double)ch[j][5]+(double)cl[j][5]) + r*g64[5]);
                part += ((1.0-z)*n + z*H1) * wo0d1;
#pragma unroll
                for (int off=32; off>0; off>>=1) part += __shfl_xor(part, off);
                if (lane == g*4+j) lv = part + dbo0d;
            }
        }

        // ---- softmax + noisy argmax (identical numerics to r9-r17) ----
        double dv = (lane < DG) ? lv : -1e300;
        double dmx = dv;
#pragma unroll
        for (int off=32; off>0; off>>=1) dmx = fmax(dmx, __shfl_xor(dmx, off));
        double de = (lane < DG) ? fexp64(dv - dmx) : 0.0;
        double ds = de;
#pragma unroll
        for (int off=32; off>0; off>>=1) ds += __shfl_xor(ds, off);
        const double dnorm = dmx + log(ds);
        double dnoisy = (lane < DG) ? fexp64(dv - dnorm) + 0.01*(double)nz : -1e300;
        int di = lane;
#pragma unroll
        for (int off=32; off>0; off>>=1){
            double ov = __shfl_xor(dnoisy, off);
            int    oi = __shfl_xor(di, off);
            if (ov > dnoisy || (ov == dnoisy && oi < di)){ dnoisy = ov; di = oi; }
        }
        const double lpfix = __shfl(dv, di) - dnorm;
        if (active && lane == 0) out[NN*CD + node*TT + t] = (float)lpfix;
        const int newcur = __shfl(nbrv, di);
        diverged = diverged || (newcur != pw[t+1]);
        cur = newcur;
    }

    if (active && diverged && lane == 0){
        int* p = paths + (size_t)node*8;
        p[0]=c0; p[1]=c1; p[2]=c2; p[3]=c3; p[4]=cur;
    }
}

// w-GRU over the recorded 5-node walk; cooperative matvec with 3-stage
// reduction (14.3KB LDS, r18).
__global__ __launch_bounds__(256) void wgru_kernel(
    const int*   __restrict__ paths, const float* __restrict__ XGwP,
    const float* __restrict__ wWhP,  const float* __restrict__ wbh,
    const float* __restrict__ wWo,   const float* __restrict__ wbo,
    float* __restrict__ out)
{
    __shared__ float hw_s[4][HD];            // 2 KB
    __shared__ float dbuf_s[2][4][6][64];    // 12 KB
    const int wid  = threadIdx.x >> 6;
    const int lane = threadIdx.x & 63;
    const int node = blockIdx.x*4 + wid;

    float h0 = 0.f, h1 = 0.f;
    float wb[6], hg[6];
#pragma unroll
    for (int m=0;m<6;m++){ wb[m] = wbh[lane+64*m]; hg[m] = wb[m]; }
    const int* p = paths + (size_t)node*8;

#pragma unroll
    for (int s=0; s<=TT; s++){
        const int c = p[s];
        const float4* xr = (const float4*)(XGwP + ((size_t)c*64 + lane)*8);
        const float4 A = xr[0], B = xr[1];
        float r = fsig (A.x + hg[0]);
        float z = fsig (A.z + hg[2]);
        float n = ftanh(B.x + r*hg[4]);
        h0 = (1.f-z)*n + z*h0;
        r = fsig (A.y + hg[1]);
        z = fsig (A.w + hg[3]);
        n = ftanh(B.y + r*hg[5]);
        h1 = (1.f-z)*n + z*h1;
        if (s < TT){
            hw_s[wid][lane] = h0;  hw_s[wid][lane+64] = h1;
            __syncthreads();
            float pacc[4][6];
#pragma unroll
            for (int j=0;j<4;j++)
#pragma unroll
                for (int m=0;m<6;m++) pacc[j][m] = 0.f;
            const float4* wr = (const float4*)(wWhP + (size_t)lane*8);
#pragma unroll 4
            for (int kk=0; kk<32; kk++){
                const int k = wid*32 + kk;
                const float4 W0 = wr[k*128], W1 = wr[k*128+1];
#pragma unroll
                for (int j=0;j<4;j++){
                    const float hk = hw_s[j][k];
                    pacc[j][0] += hk*W0.x; pacc[j][1] += hk*W0.y;
                    pacc[j][2] += hk*W0.z; pacc[j][3] += hk*W0.w;
                    pacc[j][4] += hk*W1.x; pacc[j][5] += hk*W1.y;
                }
            }
            if (wid >= 2){
#pragma unroll
                for (int j=0;j<4;j++)
#pragma unroll
                    for (int m=0;m<6;m++) dbuf_s[wid-2][j][m][lane] = pacc[j][m];
            }
            __syncthreads();
            if (wid < 2){
#pragma unroll
                for (int j=0;j<4;j++)
#pragma unroll
                    for (int m=0;m<6;m++){
                        pacc[j][m] += dbuf_s[wid][j][m][lane];
                        dbuf_s[wid][j][m][lane] = pacc[j][m];
                    }
            }
            __syncthreads();
#pragma unroll
            for (int m=0;m<6;m++)
                hg[m] = wb[m] + dbuf_s[0][wid][m][lane] + dbuf_s[1][wid][m][lane];
        }
    }
    hw_s[wid][lane] = h0;  hw_s[wid][lane+64] = h1;
    __syncthreads();

    float acc = wbo[lane];                 // CD == 64 == wave width
    const float* wcol = wWo + lane;
    for (int i=0;i<HD;i++) acc += hw_s[wid][i] * wcol[(size_t)i*CD];
    out[(size_t)node*CD + lane] = acc;
}

extern "C" void kernel_launch(void* const* d_in, const int* in_sizes, int n_in,
                              void* d_out, int out_size, void* d_ws, size_t ws_size,
                              hipStream_t stream)
{
    const float* attr  = (const float*)d_in[0];
    const int*   nbrs  = (const int*)  d_in[1];
    const float* noise = (const float*)d_in[2];
    const float* dWx = (const float*)d_in[3];
    const float* dWh = (const float*)d_in[4];
    const float* dbx = (const float*)d_in[5];
    const float* dbh = (const float*)d_in[6];
    const float* dWo = (const float*)d_in[7];
    const float* dbo = (const float*)d_in[8];
    const float* wWx = (const float*)d_in[9];
    const float* wWh = (const float*)d_in[10];
    const float* wbx = (const float*)d_in[11];
    const float* wbh = (const float*)d_in[12];
    const float* wWo = (const float*)d_in[13];
    const float* wbo = (const float*)d_in[14];
    float* out = (float*)d_out;

    char* ws = (char*)d_ws;
    float* XGfP      = (float*)(ws);                 // 16,384,000 B
    float* XGrP      = (float*)(ws + 16384000);      // 12,288,000 B
    float* XGwP      = (float*)(ws + 28672000);      // 16,384,000 B
    float* dWhP      = (float*)(ws + 45056000);      // 262,144 B
    float* wWhP      = (float*)(ws + 45318144);      // 262,144 B
    int*   paths     = (int*)  (ws + 45580288);      // 256,000 B
    int*   fail_list = (int*)  (ws + 45836288);      // 4 bins x 32,000 B
    int*   fail_cnt  = (int*)  (ws + 45964288);      // 16 B  (total ~46.0 MB)

    hipMemsetAsync(fail_cnt, 0, 4*sizeof(int), stream);

    xg_kernel<<<NN/8, G3, 0, stream>>>(attr, dWx, dbx, XGfP, XGrP);
    xg_kernel<<<NN/8, G3, 0, stream>>>(attr, wWx, wbx, XGwP, nullptr);
    repack_kernel<<<(HD*64*8)/256, 256, 0, stream>>>(dWh, dWhP);
    repack_kernel<<<(HD*64*8)/256, 256, 0, stream>>>(wWh, wWhP);

    walk_kernel<<<NN/4, 256, 0, stream>>>(nbrs, noise, XGfP, dWhP,
                                          dbh, dWo, dbo,
                                          paths, fail_cnt, fail_list, out);
    fix_kernel<<<2000, 256, 0, stream>>>(nbrs, noise, XGfP, XGrP,
                                         dWhP, dbh, dWo, dbo,
                                         fail_cnt, fail_list, paths, out);
    wgru_kernel<<<NN/4, 256, 0, stream>>>(paths, XGwP, wWhP, wbh, wWo, wbo, out);
}

// Round 19
// 466.044 us; speedup vs baseline: 1.1634x; 1.0442x over previous
//
#include <hip/hip_runtime.h>
#include <math.h>

#define NN 8000   // nodes
#define CD 64     // node feature dim / C_OUT
#define DG 16     // neighbors per node
#define HD 128    // GRU hidden
#define G3 384    // 3*HD
#define TT 4      // walk steps
// Worst-case f32 noisy-score error bound ~1e-3; MARGIN = 4e-3 (proven r8-r18).
#define MARGIN 4e-3f

#if __has_builtin(__builtin_amdgcn_rcpf)
#define RCP(x) __builtin_amdgcn_rcpf(x)
#else
#define RCP(x) (1.f/(x))
#endif

// fast f32 (walk + wgru; error ~1e-6 << MARGIN)
__device__ __forceinline__ float fsig (float x){ return RCP(1.f + __expf(-x)); }
__device__ __forceinline__ float ftanh(float x){ return 1.f - 2.f*RCP(1.f + __expf(2.f*x)); }

// fast f64 exp: range-reduced 13-term Horner, ~3 ulp (validated r9-r18).
__device__ __forceinline__ double fexp64(double x){
    const double LOG2E  = 1.4426950408889634074;
    const double LN2_HI = 6.93147180369123816490e-01;
    const double LN2_LO = 1.90821492927058770002e-10;
    x = fmin(fmax(x, -700.0), 700.0);
    double fn = rint(x * LOG2E);
    double r  = fma(-fn, LN2_HI, x);
    r = fma(-fn, LN2_LO, r);
    double p = 1.6059043836821613e-10;            // 1/13!
    p = fma(p, r, 2.0876756987868099e-09);
    p = fma(p, r, 2.5052108385441719e-08);
    p = fma(p, r, 2.7557319223985893e-07);
    p = fma(p, r, 2.7557319223985888e-06);
    p = fma(p, r, 2.4801587301587302e-05);
    p = fma(p, r, 1.9841269841269841e-04);
    p = fma(p, r, 1.3888888888888889e-03);
    p = fma(p, r, 8.3333333333333332e-03);
    p = fma(p, r, 4.1666666666666664e-02);
    p = fma(p, r, 1.6666666666666666e-01);
    p = fma(p, r, 0.5);
    p = fma(p, r, 1.0);
    p = fma(p, r, 1.0);
    long long bits = __double_as_longlong(p) + ((long long)(int)fn << 52);
    return __longlong_as_double(bits);
}
__device__ __forceinline__ double sig64f (double x){ return 1.0/(1.0 + fexp64(-x)); }
__device__ __forceinline__ double tanh64f(double x){ return 1.0 - 2.0/(fexp64(2.0*x) + 1.0); }

// XG precompute in f64; emit SPLIT packed tables (r19 — no zero padding):
//   hiA[n][64][4] = slots 0-3 (float4-aligned), hiB[n][64][2] = slots 4,5
//   (+ optional residual loP[n][64][6]). Slot q of lane l = XG[n][64*q + l].
__global__ __launch_bounds__(384) void xg_kernel(const float* __restrict__ A,
    const float* __restrict__ W, const float* __restrict__ b,
    float* __restrict__ hiA, float* __restrict__ hiB, float* __restrict__ loP)
{
    __shared__ float a_s[8][64];
    const int g  = threadIdx.x;        // 0..383
    const int l  = g & 63, q = g >> 6;
    const int n0 = blockIdx.x * 8;
    for (int idx = threadIdx.x; idx < 8*64; idx += 384)
        a_s[idx>>6][idx&63] = A[(size_t)n0*64 + idx];
    __syncthreads();
    double acc[8];
    const double bg = (double)b[g];
#pragma unroll
    for (int j=0;j<8;j++) acc[j] = bg;
    for (int c=0;c<64;c++){
        const double w = (double)W[c*G3 + g];
#pragma unroll
        for (int j=0;j<8;j++) acc[j] += (double)a_s[j][c]*w;
    }
#pragma unroll
    for (int j=0;j<8;j++){
        const size_t base = (size_t)(n0+j)*64 + l;
        const float hi = (float)acc[j];
        if (q < 4) hiA[base*4 + q]     = hi;
        else       hiB[base*2 + (q-4)] = hi;
        if (loP)   loP[base*6 + q] = (float)(acc[j] - (double)hi);
    }
}

// Repack Wh [k][384] -> [k][lane][8] (slot m = W[k][64*m+lane], slots 6,7 = 0).
__global__ __launch_bounds__(256) void repack_kernel(const float* __restrict__ W,
                                                     float* __restrict__ P)
{
    const int idx = blockIdx.x*256 + threadIdx.x;   // 0 .. 128*512-1
    const int k = idx >> 9, rem = idx & 511, l = rem >> 3, s = rem & 7;
    P[idx] = (s < 6) ? W[k*G3 + s*64 + l] : 0.f;
}

// Phase 1: pure-f32 walk, pipelined (r18) + split 24B/lane rows (r19).
// Trip mask binned by last-tripped step (r16) for the fix kernel.
__global__ __launch_bounds__(256) void walk_kernel(
    const int*   __restrict__ nbrs,  const float* __restrict__ noise,
    const float* __restrict__ XGfA,  const float* __restrict__ XGfB,
    const float* __restrict__ dWhP,
    const float* __restrict__ dbh,   const float* __restrict__ dWo,
    const float* __restrict__ dbo,
    int* __restrict__ paths, int* __restrict__ fail_cnt, int* __restrict__ fail_list,
    float* __restrict__ out)
{
    __shared__ float hf_s[4][HD];            // 2 KB
    __shared__ float dbuf_s[2][4][6][64];    // 12 KB

    const int wid  = threadIdx.x >> 6;
    const int lane = threadIdx.x & 63;
    const int node = blockIdx.x*4 + wid;

    float h0 = 0.f, h1 = 0.f;
    float dbhf[6], hgf[6];
#pragma unroll
    for (int m=0;m<6;m++){ dbhf[m] = dbh[lane+64*m]; hgf[m] = dbhf[m]; }
    const float wo0f0 = dWo[lane*CD];
    const float wo0f1 = dWo[(lane+64)*CD];
    const float dbo0f = dbo[0];

    int cur = node;
    int ch0=0, ch1=0, ch2=0, ch3=0;
    int tripmask = 0;

    // ---- pipeline preload for t=0 ----
    float4 XA; float2 XB; int nbrv; float nz;
    {
        XA = *(const float4*)(XGfA + ((size_t)cur*64 + lane)*4);
        XB = *(const float2*)(XGfB + ((size_t)cur*64 + lane)*2);
        nbrv = (lane < DG) ? nbrs[(size_t)cur*DG + lane] : 0;
        nz   = (lane < DG) ? noise[(size_t)node*DG + lane] : 0.f;
    }

    float4 PA[4], QA[4];  float2 PB[4], QB[4];
    float lf;

    auto loadGroup = [&](float4* Ab, float2* Bb, int gbase){
#pragma unroll
        for (int j=0;j<4;j++){
            const int nd = __shfl(nbrv, gbase+j);
            Ab[j] = *(const float4*)(XGfA + ((size_t)nd*64 + lane)*4);
            Bb[j] = *(const float2*)(XGfB + ((size_t)nd*64 + lane)*2);
        }
    };
    auto scoreGroup = [&](const float4* Ab, const float2* Bb, int gbase){
        float part[4];
#pragma unroll
        for (int j=0;j<4;j++){
            float r = fsig (Ab[j].x + hgf[0]);
            float z = fsig (Ab[j].z + hgf[2]);
            float n = ftanh(Bb[j].x + r*hgf[4]);
            part[j]  = ((1.f-z)*n + z*h0) * wo0f0;
            r = fsig (Ab[j].y + hgf[1]);
            z = fsig (Ab[j].w + hgf[3]);
            n = ftanh(Bb[j].y + r*hgf[5]);
            part[j] += ((1.f-z)*n + z*h1) * wo0f1;
        }
#pragma unroll
        for (int off=32; off>0; off>>=1){
#pragma unroll
            for (int j=0;j<4;j++) part[j] += __shfl_xor(part[j], off);
        }
#pragma unroll
        for (int j=0;j<4;j++) if (lane == gbase+j) lf = part[j] + dbo0f;
    };

    for (int t=0;t<TT;t++){
        if      (t==0) ch0 = cur;
        else if (t==1) ch1 = cur;
        else if (t==2) ch2 = cur;
        else           ch3 = cur;

        // ---- extend prefix (prefetched row) ----
        {
            float r = fsig (XA.x + hgf[0]);
            float z = fsig (XA.z + hgf[2]);
            float n = ftanh(XB.x + r*hgf[4]);
            h0 = (1.f-z)*n + z*h0;
            r = fsig (XA.y + hgf[1]);
            z = fsig (XA.w + hgf[3]);
            n = ftanh(XB.y + r*hgf[5]);
            h1 = (1.f-z)*n + z*h1;
        }
        hf_s[wid][lane] = h0;  hf_s[wid][lane+64] = h1;
        __syncthreads();                 // (1) all 4 nodes' h visible

        // ---- prefetch candidate group 0 (hides under the matvec) ----
        loadGroup(PA, PB, 0);

        // ---- cooperative matvec, 3-stage pairwise reduction ----
        float pacc[4][6];
#pragma unroll
        for (int j=0;j<4;j++)
#pragma unroll
            for (int m=0;m<6;m++) pacc[j][m] = 0.f;
        {
            const float4* wr = (const float4*)(dWhP + (size_t)lane*8);
#pragma unroll 4
            for (int kk=0; kk<32; kk++){
                const int k = wid*32 + kk;
                const float4 W0 = wr[k*128], W1 = wr[k*128+1];
#pragma unroll
                for (int j=0;j<4;j++){
                    const float hk = hf_s[j][k];
                    pacc[j][0] += hk*W0.x; pacc[j][1] += hk*W0.y;
                    pacc[j][2] += hk*W0.z; pacc[j][3] += hk*W0.w;
                    pacc[j][4] += hk*W1.x; pacc[j][5] += hk*W1.y;
                }
            }
        }
        if (wid >= 2){
#pragma unroll
            for (int j=0;j<4;j++)
#pragma unroll
                for (int m=0;m<6;m++) dbuf_s[wid-2][j][m][lane] = pacc[j][m];
        }
        __syncthreads();                 // (2) writers 2,3 published
        if (wid < 2){
#pragma unroll
            for (int j=0;j<4;j++)
#pragma unroll
                for (int m=0;m<6;m++){
                    pacc[j][m] += dbuf_s[wid][j][m][lane];
                    dbuf_s[wid][j][m][lane] = pacc[j][m];
                }
        }
        __syncthreads();                 // (3) pair sums published
#pragma unroll
        for (int m=0;m<6;m++)
            hgf[m] = dbhf[m] + dbuf_s[0][wid][m][lane] + dbuf_s[1][wid][m][lane];

        // ---- 16 candidates: double-buffered groups of 4 ----
        lf = -3.0e38f;
        loadGroup(QA, QB, 4);   scoreGroup(PA, PB, 0);
        loadGroup(PA, PB, 8);   scoreGroup(QA, QB, 4);
        loadGroup(QA, QB, 12);  scoreGroup(PA, PB, 8);
        scoreGroup(QA, QB, 12);

        // ---- softmax + noisy argmax + top-2 margin ----
        float v  = (lane < DG) ? lf : -3.0e38f;
        float mx = v;
#pragma unroll
        for (int off=32; off>0; off>>=1) mx = fmaxf(mx, __shfl_xor(mx, off));
        float e = (lane < DG) ? __expf(v - mx) : 0.f;
        float s = e;
#pragma unroll
        for (int off=32; off>0; off>>=1) s += __shfl_xor(s, off);
        const float normf = mx + __logf(s);

        float noisyf = (lane < DG) ? __expf(v - normf) + 0.01f*nz : -3.0e38f;
        int   idx = lane;
        float bv  = noisyf;
#pragma unroll
        for (int off=32; off>0; off>>=1){
            float ov = __shfl_xor(bv, off);
            int   oi = __shfl_xor(idx, off);
            if (ov > bv || (ov == bv && oi < idx)){ bv = ov; idx = oi; }
        }
        float sv = (lane == idx || lane >= DG) ? -3.0e38f : noisyf;
#pragma unroll
        for (int off=32; off>0; off>>=1) sv = fmaxf(sv, __shfl_xor(sv, off));

        if ((bv - sv) < MARGIN) tripmask |= (1 << t);   // wave-uniform

        const float lpf = __shfl(v, idx) - normf;
        if (lane == 0) out[NN*CD + node*TT + t] = lpf;
        cur = __shfl(nbrv, idx);

        // ---- prefetch next step's row / neighbors / noise ----
        if (t < TT-1){
            XA = *(const float4*)(XGfA + ((size_t)cur*64 + lane)*4);
            XB = *(const float2*)(XGfB + ((size_t)cur*64 + lane)*2);
            nbrv = (lane < DG) ? nbrs[(size_t)cur*DG + lane] : 0;
            nz   = (lane < DG) ? noise[((size_t)(t+1)*NN + node)*DG + lane] : 0.f;
        }
    }

    if (lane == 0){
        int* p = paths + (size_t)node*8;
        p[0]=ch0; p[1]=ch1; p[2]=ch2; p[3]=ch3; p[4]=cur;
        if (tripmask){
            const int bin = 31 - __clz(tripmask);   // last tripped step 0..3
            const int slot = atomicAdd(&fail_cnt[bin], 1);
            fail_list[bin*NN + slot] = node | (tripmask << 16);
        }
    }
}

// Phase 2: exact-f64 redo (r17 logic, split-table addressing r19; all computed
// f64 values bit-identical — same floats, same add order).
__global__ __launch_bounds__(256) void fix_kernel(
    const int*   __restrict__ nbrs,  const float* __restrict__ noise,
    const float* __restrict__ XGfA,  const float* __restrict__ XGfB,
    const float* __restrict__ XGrP,
    const float* __restrict__ dWhP,  const float* __restrict__ dbh,
    const float* __restrict__ dWo,   const float* __restrict__ dbo,
    const int* __restrict__ fail_cnt, const int* __restrict__ fail_list,
    int* __restrict__ paths, float* __restrict__ out)
{
    __shared__ double smem[3584];            // 28672 B: h_s[512] + dbuf[3072]
    double* h_s  = smem;                     // [4][HD]
    double* dbuf = smem + 512;               // [2][4][6][64]

    const int wid  = threadIdx.x >> 6;
    const int lane = threadIdx.x & 63;
    const int n0c = fail_cnt[0], n1c = fail_cnt[1], n2c = fail_cnt[2], n3c = fail_cnt[3];
    const int total = n0c + n1c + n2c + n3c;
    if (blockIdx.x*4 >= total) return;       // whole-block early exit (uniform)

    const int  ii     = blockIdx.x*4 + wid;
    const bool active = (ii < total);
    int entry = 0;
    if (active){
        int b, loc;
        if      (ii < n0c)            { b=0; loc=ii; }
        else if (ii < n0c+n1c)        { b=1; loc=ii-n0c; }
        else if (ii < n0c+n1c+n2c)    { b=2; loc=ii-n0c-n1c; }
        else                          { b=3; loc=ii-n0c-n1c-n2c; }
        entry = fail_list[b*NN + loc];
    }
    const int  node = entry & 0xFFFF;
    const int  mask = active ? (entry >> 16) : 0;   // idle: done immediately
    const int* pw   = paths + (size_t)node*8;

    double db64[6];
#pragma unroll
    for (int m=0;m<6;m++) db64[m] = (double)dbh[lane+64*m];
    const double wo0d0 = (double)dWo[lane*CD];
    const double wo0d1 = (double)dWo[(lane+64)*CD];
    const double dbo0d = (double)dbo[0];

    double H0 = 0.0, H1 = 0.0;
    double g64[6];
#pragma unroll
    for (int m=0;m<6;m++) g64[m] = db64[m];
    int  cur = node;
    int  c0=0,c1=0,c2=0,c3=0;
    bool diverged = false;

    for (int t=0;t<TT;t++){
        const bool done = !diverged && ((mask >> t) == 0);
        if (__syncthreads_and(done ? 1 : 0)) break;   // block-uniform

        if      (t==0) c0 = cur;
        else if (t==1) c1 = cur;
        else if (t==2) c2 = cur;
        else           c3 = cur;

        // ---- extend (f64 = hi + residual); skipped for done waves ----
        if (!done){
            const size_t b = (size_t)cur*64 + lane;
            const float4 ha = *(const float4*)(XGfA + b*4);
            const float2 hb = *(const float2*)(XGfB + b*2);
            const float* lo = XGrP + b*6;
            double r = sig64f (((double)ha.x+(double)lo[0]) + g64[0]);
            double z = sig64f (((double)ha.z+(double)lo[2]) + g64[2]);
            double n = tanh64f(((double)hb.x+(double)lo[4]) + r*g64[4]);
            H0 = (1.0-z)*n + z*H0;
            r = sig64f (((double)ha.y+(double)lo[1]) + g64[1]);
            z = sig64f (((double)ha.w+(double)lo[3]) + g64[3]);
            n = tanh64f(((double)hb.y+(double)lo[5]) + r*g64[5]);
            H1 = (1.0-z)*n + z*H1;
            h_s[wid*HD + lane] = H0;  h_s[wid*HD + lane + 64] = H1;
        }
        __syncthreads();                            // (1) h ready

        // ---- cooperative f64 matvec, 3-stage pairwise reduction (28KB) ----
        double pacc[4][6];
#pragma unroll
        for (int j=0;j<4;j++)
#pragma unroll
            for (int m=0;m<6;m++) pacc[j][m] = 0.0;
        {
            const float4* wv = (const float4*)(dWhP + (size_t)lane*8);
#pragma unroll 4
            for (int kk=0; kk<32; kk++){
                const int k = wid*32 + kk;
                const float4 W0 = wv[k*128], W1 = wv[k*128+1];
#pragma unroll
                for (int j=0;j<4;j++){
                    const double hk = h_s[j*HD + k];
                    pacc[j][0] += hk*(double)W0.x; pacc[j][1] += hk*(double)W0.y;
                    pacc[j][2] += hk*(double)W0.z; pacc[j][3] += hk*(double)W0.w;
                    pacc[j][4] += hk*(double)W1.x; pacc[j][5] += hk*(double)W1.y;
                }
            }
        }
        if (wid >= 2){
#pragma unroll
            for (int j=0;j<4;j++)
#pragma unroll
                for (int m=0;m<6;m++)
                    dbuf[(((wid-2)*4+j)*6+m)*64 + lane] = pacc[j][m];
        }
        __syncthreads();                            // (2) writers 2,3 published
        if (wid < 2){
#pragma unroll
            for (int j=0;j<4;j++)
#pragma unroll
                for (int m=0;m<6;m++){
                    pacc[j][m] += dbuf[((wid*4+j)*6+m)*64 + lane];
                    dbuf[((wid*4+j)*6+m)*64 + lane] = pacc[j][m];
                }
        }
        __syncthreads();                            // (3) pair sums published
        if (!done){
#pragma unroll
            for (int m=0;m<6;m++)
                g64[m] = db64[m] + dbuf[((0*4+wid)*6+m)*64 + lane]
                                 + dbuf[((1*4+wid)*6+m)*64 + lane];
        }

        // ---- certified step (not tripped, on recorded path): skip scoring ----
        if (!diverged && !((mask >> t) & 1)){
            cur = pw[t+1];
            continue;                               // no barriers below — safe
        }

        // ---- 16 candidates f64, 4 groups of 4 with prefetch ----
        int   nbrv = (lane < DG) ? nbrs[(size_t)cur*DG + lane] : 0;
        float nz   = (lane < DG) ? noise[((size_t)t*NN + node)*DG + lane] : 0.f;
        double lv = -1e300;
#pragma unroll
        for (int g=0; g<4; g++){
            float4 ca[4]; float2 cb[4]; float cl[4][6];
#pragma unroll
            for (int j=0;j<4;j++){
                const int nd = __shfl(nbrv, g*4+j);
                const size_t b = (size_t)nd*64 + lane;
                ca[j] = *(const float4*)(XGfA + b*4);
                cb[j] = *(const float2*)(XGfB + b*2);
                const float* lo = XGrP + b*6;
#pragma unroll
                for (int q=0;q<6;q++) cl[j][q] = lo[q];
            }
#pragma unroll
            for (int j=0;j<4;j++){
                double r = sig64f (((double)ca[j].x+(double)cl[j][0]) + g64[0]);
                double z = sig64f (((double)ca[j].z+(double)cl[j][2]) + g64[2]);
                double n = tanh64f(((double)cb[j].x+(double)cl[j][4]) + r*g64[4]);
                double part = ((1.0-z)*n + z*H0) * wo0d0;
                r = sig64f (((double)ca[j].y+(double)cl[j][1]) + g64[1]);
                z = sig64f (((double)ca[j].w+(double)cl[j][3]) + g64[3]);
                n = tanh64f(((double)cb[j].y+(double)cl[j][5]) + r*g64[5]);
                part += ((1.0-z)*n + z*H1) * wo0d1;
#pragma unroll
                for (int off=32; off>0; off>>=1) part += __shfl_xor(part, off);
                if (lane == g*4+j) lv = part + dbo0d;
            }
        }

        // ---- softmax + noisy argmax (identical numerics to r9-r18) ----
        double dv = (lane < DG) ? lv : -1e300;
        double dmx = dv;
#pragma unroll
        for (int off=32; off>0; off>>=1) dmx = fmax(dmx, __shfl_xor(dmx, off));
        double de = (lane < DG) ? fexp64(dv - dmx) : 0.0;
        double ds = de;
#pragma unroll
        for (int off=32; off>0; off>>=1) ds += __shfl_xor(ds, off);
        const double dnorm = dmx + log(ds);
        double dnoisy = (lane < DG) ? fexp64(dv - dnorm) + 0.01*(double)nz : -1e300;
        int di = lane;
#pragma unroll
        for (int off=32; off>0; off>>=1){
            double ov = __shfl_xor(dnoisy, off);
            int    oi = __shfl_xor(di, off);
            if (ov > dnoisy || (ov == dnoisy && oi < di)){ dnoisy = ov; di = oi; }
        }
        const double lpfix = __shfl(dv, di) - dnorm;
        if (active && lane == 0) out[NN*CD + node*TT + t] = (float)lpfix;
        const int newcur = __shfl(nbrv, di);
        diverged = diverged || (newcur != pw[t+1]);
        cur = newcur;
    }

    if (active && diverged && lane == 0){
        int* p = paths + (size_t)node*8;
        p[0]=c0; p[1]=c1; p[2]=c2; p[3]=c3; p[4]=cur;
    }
}

// w-GRU over the recorded 5-node walk; split tables + 3-stage reduction.
__global__ __launch_bounds__(256) void wgru_kernel(
    const int*   __restrict__ paths,
    const float* __restrict__ XGwA,  const float* __restrict__ XGwB,
    const float* __restrict__ wWhP,  const float* __restrict__ wbh,
    const float* __restrict__ wWo,   const float* __restrict__ wbo,
    float* __restrict__ out)
{
    __shared__ float hw_s[4][HD];            // 2 KB
    __shared__ float dbuf_s[2][4][6][64];    // 12 KB
    const int wid  = threadIdx.x >> 6;
    const int lane = threadIdx.x & 63;
    const int node = blockIdx.x*4 + wid;

    float h0 = 0.f, h1 = 0.f;
    float wb[6], hg[6];
#pragma unroll
    for (int m=0;m<6;m++){ wb[m] = wbh[lane+64*m]; hg[m] = wb[m]; }
    const int* p = paths + (size_t)node*8;

#pragma unroll
    for (int s=0; s<=TT; s++){
        const int c = p[s];
        const size_t b = (size_t)c*64 + lane;
        const float4 A = *(const float4*)(XGwA + b*4);
        const float2 B = *(const float2*)(XGwB + b*2);
        float r = fsig (A.x + hg[0]);
        float z = fsig (A.z + hg[2]);
        float n = ftanh(B.x + r*hg[4]);
        h0 = (1.f-z)*n + z*h0;
        r = fsig (A.y + hg[1]);
        z = fsig (A.w + hg[3]);
        n = ftanh(B.y + r*hg[5]);
        h1 = (1.f-z)*n + z*h1;
        if (s < TT){
            hw_s[wid][lane] = h0;  hw_s[wid][lane+64] = h1;
            __syncthreads();
            float pacc[4][6];
#pragma unroll
            for (int j=0;j<4;j++)
#pragma unroll
                for (int m=0;m<6;m++) pacc[j][m] = 0.f;
            const float4* wr = (const float4*)(wWhP + (size_t)lane*8);
#pragma unroll 4
            for (int kk=0; kk<32; kk++){
                const int k = wid*32 + kk;
                const float4 W0 = wr[k*128], W1 = wr[k*128+1];
#pragma unroll
                for (int j=0;j<4;j++){
                    const float hk = hw_s[j][k];
                    pacc[j][0] += hk*W0.x; pacc[j][1] += hk*W0.y;
                    pacc[j][2] += hk*W0.z; pacc[j][3] += hk*W0.w;
                    pacc[j][4] += hk*W1.x; pacc[j][5] += hk*W1.y;
                }
            }
            if (wid >= 2){
#pragma unroll
                for (int j=0;j<4;j++)
#pragma unroll
                    for (int m=0;m<6;m++) dbuf_s[wid-2][j][m][lane] = pacc[j][m];
            }
            __syncthreads();
            if (wid < 2){
#pragma unroll
                for (int j=0;j<4;j++)
#pragma unroll
                    for (int m=0;m<6;m++){
                        pacc[j][m] += dbuf_s[wid][j][m][lane];
                        dbuf_s[wid][j][m][lane] = pacc[j][m];
                    }
            }
            __syncthreads();
#pragma unroll
            for (int m=0;m<6;m++)
                hg[m] = wb[m] + dbuf_s[0][wid][m][lane] + dbuf_s[1][wid][m][lane];
        }
    }
    hw_s[wid][lane] = h0;  hw_s[wid][lane+64] = h1;
    __syncthreads();

    float acc = wbo[lane];                 // CD == 64 == wave width
    const float* wcol = wWo + lane;
    for (int i=0;i<HD;i++) acc += hw_s[wid][i] * wcol[(size_t)i*CD];
    out[(size_t)node*CD + lane] = acc;
}

extern "C" void kernel_launch(void* const* d_in, const int* in_sizes, int n_in,
                              void* d_out, int out_size, void* d_ws, size_t ws_size,
                              hipStream_t stream)
{
    const float* attr  = (const float*)d_in[0];
    const int*   nbrs  = (const int*)  d_in[1];
    const float* noise = (const float*)d_in[2];
    const float* dWx = (const float*)d_in[3];
    const float* dWh = (const float*)d_in[4];
    const float* dbx = (const float*)d_in[5];
    const float* dbh = (const float*)d_in[6];
    const float* dWo = (const float*)d_in[7];
    const float* dbo = (const float*)d_in[8];
    const float* wWx = (const float*)d_in[9];
    const float* wWh = (const float*)d_in[10];
    const float* wbx = (const float*)d_in[11];
    const float* wbh = (const float*)d_in[12];
    const float* wWo = (const float*)d_in[13];
    const float* wbo = (const float*)d_in[14];
    float* out = (float*)d_out;

    char* ws = (char*)d_ws;
    float* XGfA      = (float*)(ws);                 //  8,192,000 B
    float* XGfB      = (float*)(ws +  8192000);      //  4,096,000 B
    float* XGrP      = (float*)(ws + 12288000);      // 12,288,000 B
    float* XGwA      = (float*)(ws + 24576000);      //  8,192,000 B
    float* XGwB      = (float*)(ws + 32768000);      //  4,096,000 B
    float* dWhP      = (float*)(ws + 36864000);      //    262,144 B
    float* wWhP      = (float*)(ws + 37126144);      //    262,144 B
    int*   paths     = (int*)  (ws + 37388288);      //    256,000 B
    int*   fail_list = (int*)  (ws + 37644288);      //  4 bins x 32,000 B
    int*   fail_cnt  = (int*)  (ws + 37772288);      //  16 B  (total ~37.8 MB)

    hipMemsetAsync(fail_cnt, 0, 4*sizeof(int), stream);

    xg_kernel<<<NN/8, G3, 0, stream>>>(attr, dWx, dbx, XGfA, XGfB, XGrP);
    xg_kernel<<<NN/8, G3, 0, stream>>>(attr, wWx, wbx, XGwA, XGwB, nullptr);
    repack_kernel<<<(HD*64*8)/256, 256, 0, stream>>>(dWh, dWhP);
    repack_kernel<<<(HD*64*8)/256, 256, 0, stream>>>(wWh, wWhP);

    walk_kernel<<<NN/4, 256, 0, stream>>>(nbrs, noise, XGfA, XGfB, dWhP,
                                          dbh, dWo, dbo,
                                          paths, fail_cnt, fail_list, out);
    fix_kernel<<<2000, 256, 0, stream>>>(nbrs, noise, XGfA, XGfB, XGrP,
                                         dWhP, dbh, dWo, dbo,
                                         fail_cnt, fail_list, paths, out);
    wgru_kernel<<<NN/4, 256, 0, stream>>>(paths, XGwA, XGwB, wWhP, wbh, wWo, wbo, out);
}